// Round 1
// baseline (612.824 us; speedup 1.0000x reference)
//
#include <hip/hip_runtime.h>
#include <hip/hip_bf16.h>
#include <stdint.h>

using bf16x8 = __attribute__((ext_vector_type(8))) __bf16;
using f32x4  = __attribute__((ext_vector_type(4))) float;

// ---------- helpers ----------
__device__ __forceinline__ unsigned short f2bf(float f) {
  union { float f; unsigned u; } x; x.f = f;
  unsigned r = x.u + 0x7fffu + ((x.u >> 16) & 1u);   // RNE
  return (unsigned short)(r >> 16);
}

__device__ __forceinline__ void gl_lds16(const void* g, void* l) {
  __builtin_amdgcn_global_load_lds(
      (const __attribute__((address_space(1))) void*)g,
      (__attribute__((address_space(3))) void*)l, 16, 0, 0);
}

__device__ __forceinline__ float sl1(float d) {
  float ad = fabsf(d);
  return ad < 1.f ? 0.5f * d * d : ad - 0.5f;
}
__device__ __forceinline__ float softplus_f(float x) {
  return fmaxf(x, 0.f) + log1pf(expf(-fabsf(x)));
}
__device__ __forceinline__ void anchor_of(int n, float& ax1, float& ay1, float& ax2, float& ay2) {
  int ii = n / 450;
  int rem = n - ii * 450;
  int jj = rem / 9;
  int a  = rem - jj * 9;
  const float SC[3] = {2.f, 4.f, 6.f};
  const float RA[3] = {0.5f, 1.f, 1.5f};
  float w = SC[a % 3] * RA[a / 3];
  float h = SC[a % 3];
  float cx = ii + 0.5f, cy = jj + 0.5f;
  ax1 = fminf(fmaxf(cx - w * 0.5f, 0.f), 50.f);
  ax2 = fminf(fmaxf(cx + w * 0.5f, 0.f), 50.f);
  ay1 = fminf(fmaxf(cy - h * 0.5f, 0.f), 50.f);
  ay2 = fminf(fmaxf(cy + h * 0.5f, 0.f), 50.f);
}

// ---------- 1. features NCHW fp32 -> padded NHWC bf16 [16][52][66][512] ----------
__global__ __launch_bounds__(256) void k_featT(const float* __restrict__ feat,
                                               unsigned short* __restrict__ featT) {
  int row = blockIdx.x;            // b*50 + i
  int b = row / 50, i = row % 50;
  int wave = threadIdx.x >> 6, lane = threadIdx.x & 63;
  if (lane >= 50) return;
  size_t rbase = (size_t)b * 1280000 + (size_t)i * 50 + lane;        // + ci*2500
  size_t wbase = (((size_t)(b * 52 + i + 1)) * 66 + (lane + 1)) * 512; // + ci
  for (int c0 = wave * 8; c0 < 512; c0 += 32) {
    __align__(16) unsigned short tmp[8];
#pragma unroll
    for (int t = 0; t < 8; ++t) tmp[t] = f2bf(feat[rbase + (size_t)(c0 + t) * 2500]);
    *(uint4*)(featT + wbase + c0) = *(const uint4*)tmp;
  }
}

// ---------- 2. conv weights [co][ci][3][3] fp32 -> [co][tap*512+ci] bf16 ----------
__global__ __launch_bounds__(256) void k_w1t(const float* __restrict__ w1,
                                             unsigned short* __restrict__ w1t) {
  int idx = blockIdx.x * 256 + threadIdx.x;   // co*512+ci, < 262144
  int co = idx >> 9, ci = idx & 511;
  const float* s = w1 + (size_t)idx * 9;
  unsigned short* d = w1t + (size_t)co * 4608 + ci;
#pragma unroll
  for (int tap = 0; tap < 9; ++tap) d[tap * 512] = f2bf(s[tap]);
}

// ---------- 3. head weights -> bf16 [48][512] (rows 0..8 cls, 9..44 box, 45..47 zero) ----------
__global__ __launch_bounds__(256) void k_wh(const float* __restrict__ wc,
                                            const float* __restrict__ wb,
                                            unsigned short* __restrict__ wh) {
  int idx = blockIdx.x * 256 + threadIdx.x;   // < 48*512
  int n = idx >> 9, ci = idx & 511;
  float v = 0.f;
  if (n < 9) v = wc[n * 512 + ci];
  else if (n < 45) v = wb[(n - 9) * 512 + ci];
  wh[idx] = f2bf(v);
}

// ---------- 4. IoU pass: full tensor + per-(b,gt) max ----------
__global__ __launch_bounds__(256) void k_iou(const float* __restrict__ gt_boxes,
                                             float* __restrict__ ioub,
                                             unsigned* __restrict__ mx) {
  int b = blockIdx.y;
  int n = blockIdx.x * 256 + threadIdx.x;
  float lm[16];
#pragma unroll
  for (int m = 0; m < 16; ++m) lm[m] = 0.f;
  if (n < 22500) {
    float ax1, ay1, ax2, ay2;
    anchor_of(n, ax1, ay1, ax2, ay2);
    float aarea = (ax2 - ax1) * (ay2 - ay1);
    float* dst = ioub + ((size_t)b * 22500 + n) * 16;
#pragma unroll
    for (int m = 0; m < 16; ++m) {
      const float* g = gt_boxes + (b * 16 + m) * 4;
      float gx1 = g[0] * 0.0625f, gy1 = g[1] * 0.0625f;
      float gx2 = g[2] * 0.0625f, gy2 = g[3] * 0.0625f;
      float ix1 = fmaxf(ax1, gx1), iy1 = fmaxf(ay1, gy1);
      float ix2 = fminf(ax2, gx2), iy2 = fminf(ay2, gy2);
      float inter = fmaxf(ix2 - ix1, 0.f) * fmaxf(iy2 - iy1, 0.f);
      float garea = (gx2 - gx1) * (gy2 - gy1);
      float iou = inter / (aarea + garea - inter + 1e-8f);
      dst[m] = iou;
      lm[m] = iou;
    }
  }
  __shared__ float red[4][16];
#pragma unroll
  for (int m = 0; m < 16; ++m) {
    float v = lm[m];
    for (int o = 32; o; o >>= 1) v = fmaxf(v, __shfl_down(v, o, 64));
    if ((threadIdx.x & 63) == 0) red[threadIdx.x >> 6][m] = v;
  }
  __syncthreads();
  if (threadIdx.x < 16) {
    float v = fmaxf(fmaxf(red[0][threadIdx.x], red[1][threadIdx.x]),
                    fmaxf(red[2][threadIdx.x], red[3][threadIdx.x]));
    atomicMax(mx + b * 16 + threadIdx.x, __float_as_uint(v));
  }
}

// ---------- 5. conv implicit GEMM: C[co][m'] = w1t * im2col(featT) ----------
// m' = rowIdx*64 + j (j<64 padded, j<50 valid), rowIdx = b*50+i. K = 4608, BK=32.
__global__ __launch_bounds__(256, 2) void k_conv(const unsigned short* __restrict__ featT,
                                                 const unsigned short* __restrict__ w1t,
                                                 const float* __restrict__ b1,
                                                 unsigned short* __restrict__ xbf) {
  __shared__ __align__(16) unsigned short sA[128 * 32];
  __shared__ __align__(16) unsigned short sB[128 * 32];
  const int tid = threadIdx.x, lane = tid & 63, wave = tid >> 6;
  const int mtile = blockIdx.x, co0 = blockIdx.y * 128;

  // staging: chunk c=tid (rows 0..63) and c=tid+256 (rows 64..127), kq = tid&3
  const int colA = tid >> 2, kq = tid & 3;
  const char* gA0 = (const char*)(w1t + (size_t)(co0 + colA) * 4608 + kq * 8);
  const char* gA1 = (const char*)(w1t + (size_t)(co0 + colA + 64) * 4608 + kq * 8);
  int mp0 = mtile * 128 + colA;
  int r0 = mp0 >> 6, j0 = mp0 & 63;
  const char* gB0 = (const char*)(featT + ((size_t)((r0 / 50) * 52 + (r0 % 50)) * 66 + j0) * 512 + kq * 8);
  int mp1 = mp0 + 64;
  int r1 = mp1 >> 6, j1 = mp1 & 63;
  const char* gB1 = (const char*)(featT + ((size_t)((r1 / 50) * 52 + (r1 % 50)) * 66 + j1) * 512 + kq * 8);
  char* lA0 = (char*)sA + wave * 1024;
  char* lA1 = (char*)sA + 4096 + wave * 1024;
  char* lB0 = (char*)sB + wave * 1024;
  char* lB1 = (char*)sB + 4096 + wave * 1024;

  const int wco = (wave & 1) * 64, wm = (wave >> 1) * 64;
  const unsigned short* fA = sA + (wco + (lane & 15)) * 32 + (lane >> 4) * 8;
  const unsigned short* fB = sB + (wm + (lane & 15)) * 32 + (lane >> 4) * 8;

  f32x4 acc[4][4] = {};

  for (int kt = 0; kt < 144; ++kt) {
    int k0 = kt * 32;
    int tap = k0 >> 9, ci0 = k0 & 511;
    int th = tap / 3, tw = tap - th * 3;
    size_t offA = (size_t)k0 * 2;
    size_t offB = ((size_t)(th * 66 + tw) * 512 + ci0) * 2;
    gl_lds16(gA0 + offA, lA0);
    gl_lds16(gA1 + offA, lA1);
    gl_lds16(gB0 + offB, lB0);
    gl_lds16(gB1 + offB, lB1);
    __syncthreads();
    bf16x8 a[4], bv[4];
#pragma unroll
    for (int mi = 0; mi < 4; ++mi) a[mi] = *(const bf16x8*)(fA + mi * 16 * 32);
#pragma unroll
    for (int ni = 0; ni < 4; ++ni) bv[ni] = *(const bf16x8*)(fB + ni * 16 * 32);
#pragma unroll
    for (int mi = 0; mi < 4; ++mi)
#pragma unroll
      for (int ni = 0; ni < 4; ++ni)
        acc[mi][ni] = __builtin_amdgcn_mfma_f32_16x16x32_bf16(a[mi], bv[ni], acc[mi][ni], 0, 0, 0);
    __syncthreads();
  }

  // epilogue: C row = co (M), col = m' (N). row=(lane>>4)*4+r, col=lane&15.
#pragma unroll
  for (int ni = 0; ni < 4; ++ni) {
    int mp = mtile * 128 + wm + ni * 16 + (lane & 15);
    int j = mp & 63;
    if (j >= 50) continue;
    size_t mc = (size_t)(mp >> 6) * 50 + j;
#pragma unroll
    for (int mi = 0; mi < 4; ++mi) {
      int co = co0 + wco + mi * 16 + (lane >> 4) * 4;
      __align__(8) unsigned short tmp[4];
#pragma unroll
      for (int r = 0; r < 4; ++r) tmp[r] = f2bf(acc[mi][ni][r] + b1[co + r]);
      *(uint2*)(xbf + mc * 512 + co) = *(const uint2*)tmp;
    }
  }
}

// ---------- 6. head GEMM: out[m][48] = x[m][512] * wh^T + bias ----------
__global__ __launch_bounds__(256) void k_head(const unsigned short* __restrict__ xbf,
                                              const unsigned short* __restrict__ wh,
                                              const float* __restrict__ bc,
                                              const float* __restrict__ bb,
                                              float* __restrict__ oh) {
  __shared__ __align__(16) unsigned short sW[48 * 520];  // padded rows: conflict-free frags
  __shared__ __align__(16) unsigned short sX[64 * 32];
  const int tid = threadIdx.x, lane = tid & 63, wave = tid >> 6;
  const int m0 = blockIdx.x * 64;
#pragma unroll
  for (int it = 0; it < 12; ++it) {
    int cc = tid + it * 256;
    int n = cc >> 6, kq = cc & 63;
    *(uint4*)(sW + n * 520 + kq * 8) = *(const uint4*)(wh + n * 512 + kq * 8);
  }
  const char* gX = (const char*)(xbf + (size_t)(m0 + (tid >> 2)) * 512 + (tid & 3) * 8);
  char* lX = (char*)sX + wave * 1024;
  const unsigned short* fX = sX + (wave * 16 + (lane & 15)) * 32 + (lane >> 4) * 8;
  const unsigned short* fW = sW + (lane & 15) * 520 + (lane >> 4) * 8;
  f32x4 acc[3] = {};
  for (int kt = 0; kt < 16; ++kt) {
    gl_lds16(gX + kt * 64, lX);
    __syncthreads();
    bf16x8 a = *(const bf16x8*)fX;
#pragma unroll
    for (int nf = 0; nf < 3; ++nf) {
      bf16x8 b = *(const bf16x8*)(fW + nf * 16 * 520 + kt * 32);
      acc[nf] = __builtin_amdgcn_mfma_f32_16x16x32_bf16(a, b, acc[nf], 0, 0, 0);
    }
    __syncthreads();
  }
#pragma unroll
  for (int nf = 0; nf < 3; ++nf) {
    int col = nf * 16 + (lane & 15);
    if (col >= 45) continue;
    float bias = col < 9 ? bc[col] : bb[col - 9];
    int m = m0 + wave * 16 + (lane >> 4) * 4;
#pragma unroll
    for (int r = 0; r < 4; ++r) oh[(size_t)(m + r) * 48 + col] = acc[nf][r] + bias;
  }
}

// ---------- 7. loss pass: masks, loss partial sums, proposals ----------
__global__ __launch_bounds__(256) void k_loss(const float* __restrict__ gt_boxes,
                                              const float* __restrict__ ioub,
                                              const unsigned* __restrict__ mxbuf,
                                              const float* __restrict__ oh,
                                              float* __restrict__ accum,
                                              float* __restrict__ dout) {
  int b = blockIdx.y;
  int n = blockIdx.x * 256 + threadIdx.x;
  float s_np = 0.f, s_reg = 0.f, s_pos = 0.f, s_nc = 0.f, s_nl = 0.f;
  if (n < 22500) {
    float ax1, ay1, ax2, ay2;
    anchor_of(n, ax1, ay1, ax2, ay2);
    float acx = (ax1 + ax2) * 0.5f, acy = (ay1 + ay2) * 0.5f;
    float aw = fmaxf(ax2 - ax1, 1e-6f), ah = fmaxf(ay2 - ay1, 1e-6f);
    int ii = n / 450, rem = n - ii * 450, jj = rem / 9, a = rem - jj * 9;
    const float* row = oh + ((size_t)b * 2500 + ii * 50 + jj) * 48;
    float logit = row[a];
    float p0 = row[9 + a * 4], p1 = row[10 + a * 4], p2 = row[11 + a * 4], p3 = row[12 + a * 4];
    const float* ioup = ioub + ((size_t)b * 22500 + n) * 16;
    int npos = 0;
    bool allneg = true;
#pragma unroll
    for (int m = 0; m < 16; ++m) {
      float iou = ioup[m];
      float mxv = __uint_as_float(mxbuf[b * 16 + m]);
      bool pos = ((iou == mxv) && (mxv > 0.f)) || (iou > 0.7f);
      if (iou >= 0.3f) allneg = false;
      if (pos) {
        ++npos;
        const float* g = gt_boxes + (b * 16 + m) * 4;
        float gx1 = g[0] * 0.0625f, gy1 = g[1] * 0.0625f;
        float gx2 = g[2] * 0.0625f, gy2 = g[3] * 0.0625f;
        float gcx = (gx1 + gx2) * 0.5f, gcy = (gy1 + gy2) * 0.5f;
        float gw = fmaxf(gx2 - gx1, 1e-6f), gh = fmaxf(gy2 - gy1, 1e-6f);
        float tx = (gcx - acx) / aw, ty = (gcy - acy) / ah;
        float twv = logf(gw / aw), thv = logf(gh / ah);
        s_reg += sl1(tx - p0) + sl1(ty - p1) + sl1(twv - p2) + sl1(thv - p3);
      }
    }
    s_np = (float)npos;
    s_pos = (float)npos * softplus_f(-logit);
    if (allneg) { s_nc = 1.f; s_nl = softplus_f(logit); }
    float pcx = acx + p0 * aw, pcy = acy + p1 * ah;
    float pw = aw * expf(p2), ph = ah * expf(p3);
    float* o = dout + 1 + ((size_t)b * 22500 + n) * 4;
    o[0] = pcx - pw * 0.5f;
    o[1] = pcy - ph * 0.5f;
    o[2] = pcx + pw * 0.5f;
    o[3] = pcy + ph * 0.5f;
  }
  float vals[5] = {s_np, s_reg, s_pos, s_nc, s_nl};
  __shared__ float red[4][5];
#pragma unroll
  for (int q = 0; q < 5; ++q) {
    float v = vals[q];
    for (int o = 32; o; o >>= 1) v += __shfl_down(v, o, 64);
    if ((threadIdx.x & 63) == 0) red[threadIdx.x >> 6][q] = v;
  }
  __syncthreads();
  if (threadIdx.x < 5) {
    float v = red[0][threadIdx.x] + red[1][threadIdx.x] + red[2][threadIdx.x] + red[3][threadIdx.x];
    atomicAdd(accum + threadIdx.x, v);
  }
}

// ---------- 8. finalize ----------
__global__ void k_fin(const float* __restrict__ accum, float* __restrict__ dout) {
  if (threadIdx.x == 0 && blockIdx.x == 0) {
    float np = fmaxf(accum[0], 1.f);
    float nn = fmaxf(accum[3], 1.f);
    float loss = 0.5f * (accum[2] / np + accum[4] / nn) + 5.f * (accum[1] / (4.f * np));
    dout[0] = loss;
  }
}

// ---------- launch ----------
extern "C" void kernel_launch(void* const* d_in, const int* in_sizes, int n_in,
                              void* d_out, int out_size, void* d_ws, size_t ws_size,
                              hipStream_t stream) {
  const float* features = (const float*)d_in[0];
  const float* gt_boxes = (const float*)d_in[1];
  const float* w1    = (const float*)d_in[2];
  const float* b1    = (const float*)d_in[3];
  const float* w_cls = (const float*)d_in[4];
  const float* b_cls = (const float*)d_in[5];
  const float* w_box = (const float*)d_in[6];
  const float* b_box = (const float*)d_in[7];
  float* out = (float*)d_out;
  char* ws = (char*)d_ws;

  // ws layout (all 256B aligned)
  unsigned short* featT = (unsigned short*)(ws);               // 56,229,888 B
  unsigned short* w1t   = (unsigned short*)(ws + 56229888);    //  4,718,592 B
  unsigned short* wh    = (unsigned short*)(ws + 60948480);    //     49,152 B
  unsigned short* xbf   = (unsigned short*)(ws + 60997632);    // 40,960,000 B
  float*          oh    = (float*)(ws + 101957632);            //  7,680,000 B
  float*          ioub  = (float*)(ws + 109637632);            // 23,040,000 B
  unsigned*       mx    = (unsigned*)(ws + 132677632);         //      1,024 B
  float*          accum = (float*)(ws + 132678656);            //         32 B

  hipMemsetAsync(featT, 0, 56229888, stream);                  // zero pad borders
  hipMemsetAsync(ws + 132677632, 0, 1056, stream);             // maxiou + accums

  k_featT<<<800, 256, 0, stream>>>(features, featT);
  k_w1t<<<1024, 256, 0, stream>>>(w1, w1t);
  k_wh<<<96, 256, 0, stream>>>(w_cls, w_box, wh);
  k_iou<<<dim3(88, 16), 256, 0, stream>>>(gt_boxes, ioub, mx);
  k_conv<<<dim3(400, 4), 256, 0, stream>>>(featT, w1t, b1, xbf);
  k_head<<<625, 256, 0, stream>>>(xbf, wh, b_cls, b_box, oh);
  k_loss<<<dim3(88, 16), 256, 0, stream>>>(gt_boxes, ioub, mx, oh, accum, out);
  k_fin<<<1, 64, 0, stream>>>(accum, out);
}

// Round 2
// 402.224 us; speedup vs baseline: 1.5236x; 1.5236x over previous
//
#include <hip/hip_runtime.h>
#include <hip/hip_bf16.h>
#include <stdint.h>

using bf16x8 = __attribute__((ext_vector_type(8))) __bf16;
using f32x4  = __attribute__((ext_vector_type(4))) float;

// ---------- helpers ----------
__device__ __forceinline__ unsigned short f2bf(float f) {
  union { float f; unsigned u; } x; x.f = f;
  unsigned r = x.u + 0x7fffu + ((x.u >> 16) & 1u);   // RNE
  return (unsigned short)(r >> 16);
}

__device__ __forceinline__ void gl_lds16(const void* g, void* l) {
  __builtin_amdgcn_global_load_lds(
      (const __attribute__((address_space(1))) void*)g,
      (__attribute__((address_space(3))) void*)l, 16, 0, 0);
}

__device__ __forceinline__ float sl1(float d) {
  float ad = fabsf(d);
  return ad < 1.f ? 0.5f * d * d : ad - 0.5f;
}
__device__ __forceinline__ float softplus_f(float x) {
  return fmaxf(x, 0.f) + log1pf(expf(-fabsf(x)));
}
__device__ __forceinline__ void anchor_of(int n, float& ax1, float& ay1, float& ax2, float& ay2) {
  int ii = n / 450;
  int rem = n - ii * 450;
  int jj = rem / 9;
  int a  = rem - jj * 9;
  const float SC[3] = {2.f, 4.f, 6.f};
  const float RA[3] = {0.5f, 1.f, 1.5f};
  float w = SC[a % 3] * RA[a / 3];
  float h = SC[a % 3];
  float cx = ii + 0.5f, cy = jj + 0.5f;
  ax1 = fminf(fmaxf(cx - w * 0.5f, 0.f), 50.f);
  ax2 = fminf(fmaxf(cx + w * 0.5f, 0.f), 50.f);
  ay1 = fminf(fmaxf(cy - h * 0.5f, 0.f), 50.f);
  ay2 = fminf(fmaxf(cy + h * 0.5f, 0.f), 50.f);
}

// ---------- 1. features NCHW fp32 -> padded NHWC bf16 [16][52][66][512] ----------
__global__ __launch_bounds__(256) void k_featT(const float* __restrict__ feat,
                                               unsigned short* __restrict__ featT) {
  int row = blockIdx.x;            // b*50 + i
  int b = row / 50, i = row % 50;
  int wave = threadIdx.x >> 6, lane = threadIdx.x & 63;
  if (lane >= 50) return;
  size_t rbase = (size_t)b * 1280000 + (size_t)i * 50 + lane;          // + ci*2500
  size_t wbase = (((size_t)(b * 52 + i + 1)) * 66 + (lane + 1)) * 512; // + ci
  for (int c0 = wave * 8; c0 < 512; c0 += 32) {
    __align__(16) unsigned short tmp[8];
#pragma unroll
    for (int t = 0; t < 8; ++t) tmp[t] = f2bf(feat[rbase + (size_t)(c0 + t) * 2500]);
    *(uint4*)(featT + wbase + c0) = *(const uint4*)tmp;
  }
}

// ---------- 2a. compose partials: part[cz][co][kmem] = sum_{c in chunk} whead[co][c]*w1[c][kmem]
__global__ __launch_bounds__(128) void k_weff1(const float* __restrict__ w1,
                                               const float* __restrict__ wc,
                                               const float* __restrict__ wb,
                                               float* __restrict__ part) {
  __shared__ float sW[48][64];
  const int t = threadIdx.x;
  const int kmem = blockIdx.x * 128 + t;   // w1 inner index: ci*9+tap
  const int cz = blockIdx.y;
#pragma unroll
  for (int q = 0; q < 24; ++q) {
    int idx = t + q * 128;                 // < 3072
    int co = idx >> 6, cl = idx & 63;
    int c = cz * 64 + cl;
    float v = 0.f;
    if (co < 9) v = wc[co * 512 + c];
    else if (co < 45) v = wb[(co - 9) * 512 + c];
    sW[co][cl] = v;
  }
  __syncthreads();
  float acc[48];
#pragma unroll
  for (int co = 0; co < 48; ++co) acc[co] = 0.f;
  const float* w1p = w1 + (size_t)(cz * 64) * 4608 + kmem;
  for (int c4 = 0; c4 < 64; c4 += 4) {
    float f0 = w1p[(size_t)(c4 + 0) * 4608];
    float f1 = w1p[(size_t)(c4 + 1) * 4608];
    float f2 = w1p[(size_t)(c4 + 2) * 4608];
    float f3 = w1p[(size_t)(c4 + 3) * 4608];
#pragma unroll
    for (int co = 0; co < 48; ++co) {
      float4 wv = *(const float4*)&sW[co][c4];
      acc[co] += wv.x * f0 + wv.y * f1 + wv.z * f2 + wv.w * f3;
    }
  }
  float* dst = part + (size_t)cz * 221184 + kmem;
#pragma unroll
  for (int co = 0; co < 48; ++co) dst[(size_t)co * 4608] = acc[co];
}

// ---------- 2b. reduce partials + permute kmem->kout + cast bf16 ----------
__global__ __launch_bounds__(256) void k_weff2(const float* __restrict__ part,
                                               unsigned short* __restrict__ wefft) {
  int idx = blockIdx.x * 256 + threadIdx.x;   // < 221184 = 48*4608
  int co = idx / 4608;
  int ko = idx - co * 4608;                   // kout = tap*512+ci
  int tap = ko >> 9, ci = ko & 511;
  int kmem = ci * 9 + tap;
  const float* p = part + (size_t)co * 4608 + kmem;
  float s = 0.f;
#pragma unroll
  for (int cz = 0; cz < 8; ++cz) s += p[(size_t)cz * 221184];
  wefft[idx] = f2bf(s);
}

// ---------- 2c. bias_eff[co] = b_head[co] + whead[co]·b1 ----------
__global__ __launch_bounds__(64) void k_bias(const float* __restrict__ wc,
                                             const float* __restrict__ wb,
                                             const float* __restrict__ b1,
                                             const float* __restrict__ bc,
                                             const float* __restrict__ bbx,
                                             float* __restrict__ bias_eff) {
  int co = blockIdx.x, l = threadIdx.x;
  float s = 0.f;
#pragma unroll
  for (int q = 0; q < 8; ++q) {
    int c = q * 64 + l;
    float wv = co < 9 ? wc[co * 512 + c] : (co < 45 ? wb[(co - 9) * 512 + c] : 0.f);
    s += wv * b1[c];
  }
  for (int o = 32; o; o >>= 1) s += __shfl_down(s, o, 64);
  if (l == 0)
    bias_eff[co] = s + (co < 9 ? bc[co] : (co < 45 ? bbx[co - 9] : 0.f));
}

// ---------- 3. IoU pass: full tensor + per-(b,gt) max ----------
__global__ __launch_bounds__(256) void k_iou(const float* __restrict__ gt_boxes,
                                             float* __restrict__ ioub,
                                             unsigned* __restrict__ mx) {
  int b = blockIdx.y;
  int n = blockIdx.x * 256 + threadIdx.x;
  float lm[16];
#pragma unroll
  for (int m = 0; m < 16; ++m) lm[m] = 0.f;
  if (n < 22500) {
    float ax1, ay1, ax2, ay2;
    anchor_of(n, ax1, ay1, ax2, ay2);
    float aarea = (ax2 - ax1) * (ay2 - ay1);
    float* dst = ioub + ((size_t)b * 22500 + n) * 16;
#pragma unroll
    for (int m = 0; m < 16; ++m) {
      const float* g = gt_boxes + (b * 16 + m) * 4;
      float gx1 = g[0] * 0.0625f, gy1 = g[1] * 0.0625f;
      float gx2 = g[2] * 0.0625f, gy2 = g[3] * 0.0625f;
      float ix1 = fmaxf(ax1, gx1), iy1 = fmaxf(ay1, gy1);
      float ix2 = fminf(ax2, gx2), iy2 = fminf(ay2, gy2);
      float inter = fmaxf(ix2 - ix1, 0.f) * fmaxf(iy2 - iy1, 0.f);
      float garea = (gx2 - gx1) * (gy2 - gy1);
      float iou = inter / (aarea + garea - inter + 1e-8f);
      dst[m] = iou;
      lm[m] = iou;
    }
  }
  __shared__ float red[4][16];
#pragma unroll
  for (int m = 0; m < 16; ++m) {
    float v = lm[m];
    for (int o = 32; o; o >>= 1) v = fmaxf(v, __shfl_down(v, o, 64));
    if ((threadIdx.x & 63) == 0) red[threadIdx.x >> 6][m] = v;
  }
  __syncthreads();
  if (threadIdx.x < 16) {
    float v = fmaxf(fmaxf(red[0][threadIdx.x], red[1][threadIdx.x]),
                    fmaxf(red[2][threadIdx.x], red[3][threadIdx.x]));
    atomicMax(mx + b * 16 + threadIdx.x, __float_as_uint(v));
  }
}

// ---------- 4. fused conv+head implicit GEMM ----------
// C[m][co<48] partial over K-slice kz: 48x256 tile, BK=32, K=1152 per kz.
// LDS kq swizzle: phys_kq = (log_kq + (row>>1)) & 3  -> 2-way banks (free).
__global__ __launch_bounds__(256, 4) void k_conv(const unsigned short* __restrict__ featT,
                                                 const unsigned short* __restrict__ wefft,
                                                 float* __restrict__ ohp) {
  __shared__ __align__(16) unsigned short sA[48 * 32];
  __shared__ __align__(16) unsigned short sB[256 * 32];
  const int tid = threadIdx.x, lane = tid & 63, wave = tid >> 6;
  const int m0 = blockIdx.x * 256;
  const int kz = blockIdx.y;

  // A staging: threads 0..191, chunk row=tid>>2 (co), phys kq=tid&3
  const char* gA = (const char*)wefft;
  if (tid < 192) {
    int row = tid >> 2;
    int kql = ((tid & 3) - ((tid >> 3) & 3)) & 3;
    gA = (const char*)(wefft + (size_t)row * 4608 + kz * 1152 + kql * 8);
  }
  // B staging: 4 issues; issue i row = m0 + i*64 + (tid>>2), phys kq = lane&3
  const char* gB[4];
  {
    int kql = ((lane & 3) - ((lane >> 3) & 3)) & 3;
#pragma unroll
    for (int i = 0; i < 4; ++i) {
      int mm = m0 + i * 64 + (tid >> 2);
      mm = min(mm, 39999);
      int r = mm / 50, j = mm - r * 50;
      int bb = r / 50, ii = r - bb * 50;
      gB[i] = (const char*)(featT + ((size_t)((bb * 52 + ii) * 66 + j)) * 512 + kql * 8);
    }
  }
  char* dA  = (char*)sA + wave * 1024;
  char* dB0 = (char*)sB + wave * 1024;

  const int kqf = ((lane >> 4) + ((lane & 15) >> 1)) & 3;
  const char* fA = (const char*)sA + (lane & 15) * 64 + kqf * 16;
  const char* fB = (const char*)sB + (wave * 64 + (lane & 15)) * 64 + kqf * 16;

  f32x4 acc[3][4] = {};

  for (int kt = 0; kt < 36; ++kt) {
    int k0 = kz * 1152 + kt * 32;
    int tap = k0 >> 9;
    int ci0 = k0 & 511;
    int th = tap / 3, tw = tap - th * 3;
    size_t offB = ((size_t)(th * 66 + tw) * 512 + ci0) * 2;
    if (wave < 3) gl_lds16(gA + (size_t)kt * 64, dA);
    gl_lds16(gB[0] + offB, dB0);
    gl_lds16(gB[1] + offB, dB0 + 4096);
    gl_lds16(gB[2] + offB, dB0 + 8192);
    gl_lds16(gB[3] + offB, dB0 + 12288);
    __syncthreads();
    bf16x8 a[3], bv[4];
#pragma unroll
    for (int mi = 0; mi < 3; ++mi) a[mi] = *(const bf16x8*)(fA + mi * 1024);
#pragma unroll
    for (int ni = 0; ni < 4; ++ni) bv[ni] = *(const bf16x8*)(fB + ni * 1024);
#pragma unroll
    for (int mi = 0; mi < 3; ++mi)
#pragma unroll
      for (int ni = 0; ni < 4; ++ni)
        acc[mi][ni] = __builtin_amdgcn_mfma_f32_16x16x32_bf16(a[mi], bv[ni], acc[mi][ni], 0, 0, 0);
    __syncthreads();
  }

  // epilogue: D col = m (lane&15), row = co quad. float4 per (mi,ni).
#pragma unroll
  for (int ni = 0; ni < 4; ++ni) {
    int m = m0 + wave * 64 + ni * 16 + (lane & 15);
    if (m >= 40000) continue;
    float* dst = ohp + ((size_t)kz * 40000 + m) * 48 + (lane >> 4) * 4;
#pragma unroll
    for (int mi = 0; mi < 3; ++mi)
      *(f32x4*)(dst + mi * 16) = acc[mi][ni];
  }
}

// ---------- 5. loss pass: masks, loss partial sums, proposals ----------
__global__ __launch_bounds__(256) void k_loss(const float* __restrict__ gt_boxes,
                                              const float* __restrict__ ioub,
                                              const unsigned* __restrict__ mxbuf,
                                              const float* __restrict__ ohp,
                                              const float* __restrict__ bias_eff,
                                              float* __restrict__ accum,
                                              float* __restrict__ dout) {
  int b = blockIdx.y;
  int n = blockIdx.x * 256 + threadIdx.x;
  float s_np = 0.f, s_reg = 0.f, s_pos = 0.f, s_nc = 0.f, s_nl = 0.f;
  if (n < 22500) {
    float ax1, ay1, ax2, ay2;
    anchor_of(n, ax1, ay1, ax2, ay2);
    float acx = (ax1 + ax2) * 0.5f, acy = (ay1 + ay2) * 0.5f;
    float aw = fmaxf(ax2 - ax1, 1e-6f), ah = fmaxf(ay2 - ay1, 1e-6f);
    int ii = n / 450, rem = n - ii * 450, jj = rem / 9, a = rem - jj * 9;
    size_t mrow = (size_t)b * 2500 + ii * 50 + jj;
    float logit = bias_eff[a];
    float p0 = bias_eff[9 + a * 4], p1 = bias_eff[10 + a * 4];
    float p2 = bias_eff[11 + a * 4], p3 = bias_eff[12 + a * 4];
#pragma unroll
    for (int kz = 0; kz < 4; ++kz) {
      const float* rp = ohp + ((size_t)kz * 40000 + mrow) * 48;
      logit += rp[a];
      p0 += rp[9 + a * 4]; p1 += rp[10 + a * 4];
      p2 += rp[11 + a * 4]; p3 += rp[12 + a * 4];
    }
    const float* ioup = ioub + ((size_t)b * 22500 + n) * 16;
    int npos = 0;
    bool allneg = true;
#pragma unroll
    for (int m = 0; m < 16; ++m) {
      float iou = ioup[m];
      float mxv = __uint_as_float(mxbuf[b * 16 + m]);
      bool pos = ((iou == mxv) && (mxv > 0.f)) || (iou > 0.7f);
      if (iou >= 0.3f) allneg = false;
      if (pos) {
        ++npos;
        const float* g = gt_boxes + (b * 16 + m) * 4;
        float gx1 = g[0] * 0.0625f, gy1 = g[1] * 0.0625f;
        float gx2 = g[2] * 0.0625f, gy2 = g[3] * 0.0625f;
        float gcx = (gx1 + gx2) * 0.5f, gcy = (gy1 + gy2) * 0.5f;
        float gw = fmaxf(gx2 - gx1, 1e-6f), gh = fmaxf(gy2 - gy1, 1e-6f);
        float tx = (gcx - acx) / aw, ty = (gcy - acy) / ah;
        float twv = logf(gw / aw), thv = logf(gh / ah);
        s_reg += sl1(tx - p0) + sl1(ty - p1) + sl1(twv - p2) + sl1(thv - p3);
      }
    }
    s_np = (float)npos;
    s_pos = (float)npos * softplus_f(-logit);
    if (allneg) { s_nc = 1.f; s_nl = softplus_f(logit); }
    float pcx = acx + p0 * aw, pcy = acy + p1 * ah;
    float pw = aw * expf(p2), ph = ah * expf(p3);
    float* o = dout + 1 + ((size_t)b * 22500 + n) * 4;
    o[0] = pcx - pw * 0.5f;
    o[1] = pcy - ph * 0.5f;
    o[2] = pcx + pw * 0.5f;
    o[3] = pcy + ph * 0.5f;
  }
  float vals[5] = {s_np, s_reg, s_pos, s_nc, s_nl};
  __shared__ float red[4][5];
#pragma unroll
  for (int q = 0; q < 5; ++q) {
    float v = vals[q];
    for (int o = 32; o; o >>= 1) v += __shfl_down(v, o, 64);
    if ((threadIdx.x & 63) == 0) red[threadIdx.x >> 6][q] = v;
  }
  __syncthreads();
  if (threadIdx.x < 5) {
    float v = red[0][threadIdx.x] + red[1][threadIdx.x] + red[2][threadIdx.x] + red[3][threadIdx.x];
    atomicAdd(accum + threadIdx.x, v);
  }
}

// ---------- 6. finalize ----------
__global__ void k_fin(const float* __restrict__ accum, float* __restrict__ dout) {
  if (threadIdx.x == 0 && blockIdx.x == 0) {
    float np = fmaxf(accum[0], 1.f);
    float nn = fmaxf(accum[3], 1.f);
    float loss = 0.5f * (accum[2] / np + accum[4] / nn) + 5.f * (accum[1] / (4.f * np));
    dout[0] = loss;
  }
}

// ---------- launch ----------
extern "C" void kernel_launch(void* const* d_in, const int* in_sizes, int n_in,
                              void* d_out, int out_size, void* d_ws, size_t ws_size,
                              hipStream_t stream) {
  const float* features = (const float*)d_in[0];
  const float* gt_boxes = (const float*)d_in[1];
  const float* w1    = (const float*)d_in[2];
  const float* b1    = (const float*)d_in[3];
  const float* w_cls = (const float*)d_in[4];
  const float* b_cls = (const float*)d_in[5];
  const float* w_box = (const float*)d_in[6];
  const float* b_box = (const float*)d_in[7];
  float* out = (float*)d_out;
  char* ws = (char*)d_ws;

  // ws layout
  unsigned short* featT = (unsigned short*)(ws);               // 56,229,888 B
  unsigned short* wefft = (unsigned short*)(ws + 56229888);    //    442,368 B
  float*          wpart = (float*)(ws + 56672256);             //  7,077,888 B
  float*          ohp   = (float*)(ws + 63750144);             // 30,720,000 B
  float*          ioub  = (float*)(ws + 94470144);             // 23,040,000 B
  float*          beff  = (float*)(ws + 117510144);            //        192 B
  unsigned*       mx    = (unsigned*)(ws + 117510400);         //      1,024 B
  float*          accum = (float*)(ws + 117511424);            //         32 B

  hipMemsetAsync(featT, 0, 56229888, stream);                  // zero pad borders
  hipMemsetAsync(ws + 117510400, 0, 1056, stream);             // maxiou + accums

  k_featT<<<800, 256, 0, stream>>>(features, featT);
  k_weff1<<<dim3(36, 8), 128, 0, stream>>>(w1, w_cls, w_box, wpart);
  k_weff2<<<864, 256, 0, stream>>>(wpart, wefft);
  k_bias<<<48, 64, 0, stream>>>(w_cls, w_box, b1, b_cls, b_box, beff);
  k_iou<<<dim3(88, 16), 256, 0, stream>>>(gt_boxes, ioub, mx);
  k_conv<<<dim3(157, 4), 256, 0, stream>>>(featT, wefft, ohp);
  k_loss<<<dim3(88, 16), 256, 0, stream>>>(gt_boxes, ioub, mx, ohp, beff, accum, out);
  k_fin<<<1, 64, 0, stream>>>(accum, out);
}

// Round 4
// 318.920 us; speedup vs baseline: 1.9216x; 1.2612x over previous
//
#include <hip/hip_runtime.h>
#include <hip/hip_bf16.h>
#include <stdint.h>

using bf16x8 = __attribute__((ext_vector_type(8))) __bf16;
using f32x4  = __attribute__((ext_vector_type(4))) float;

// featT layout: [16][52][52][512] bf16 (row/col 0 and 51 are zero borders,
// zeroed by a full memset each call — do NOT partial-init: d_ws is re-poisoned
// 0xAA before every timed launch and R3's border-only init diverged on replay).
#define FT_W 52

// ---------- helpers ----------
__device__ __forceinline__ unsigned short f2bf(float f) {
  union { float f; unsigned u; } x; x.f = f;
  unsigned r = x.u + 0x7fffu + ((x.u >> 16) & 1u);   // RNE
  return (unsigned short)(r >> 16);
}

__device__ __forceinline__ void gl_lds16(const void* g, void* l) {
  __builtin_amdgcn_global_load_lds(
      (const __attribute__((address_space(1))) void*)g,
      (__attribute__((address_space(3))) void*)l, 16, 0, 0);
}

__device__ __forceinline__ float sl1(float d) {
  float ad = fabsf(d);
  return ad < 1.f ? 0.5f * d * d : ad - 0.5f;
}
__device__ __forceinline__ float softplus_f(float x) {
  return fmaxf(x, 0.f) + log1pf(expf(-fabsf(x)));
}
__device__ __forceinline__ void anchor_of(int n, float& ax1, float& ay1, float& ax2, float& ay2) {
  int ii = n / 450;
  int rem = n - ii * 450;
  int jj = rem / 9;
  int a  = rem - jj * 9;
  const float SC[3] = {2.f, 4.f, 6.f};
  const float RA[3] = {0.5f, 1.f, 1.5f};
  float w = SC[a % 3] * RA[a / 3];
  float h = SC[a % 3];
  float cx = ii + 0.5f, cy = jj + 0.5f;
  ax1 = fminf(fmaxf(cx - w * 0.5f, 0.f), 50.f);
  ax2 = fminf(fmaxf(cx + w * 0.5f, 0.f), 50.f);
  ay1 = fminf(fmaxf(cy - h * 0.5f, 0.f), 50.f);
  ay2 = fminf(fmaxf(cy + h * 0.5f, 0.f), 50.f);
}

// ---------- 1. features NCHW fp32 -> padded NHWC bf16 ----------
// grid (800, 4): y = channel quarter for occupancy (R2: 20% occ, latency-bound)
__global__ __launch_bounds__(256) void k_featT(const float* __restrict__ feat,
                                               unsigned short* __restrict__ featT) {
  int row = blockIdx.x;            // b*50 + i
  int cq  = blockIdx.y;            // channel quarter
  int b = row / 50, i = row % 50;
  int wave = threadIdx.x >> 6, lane = threadIdx.x & 63;
  if (lane >= 50) return;
  size_t rbase = (size_t)b * 1280000 + (size_t)i * 50 + lane;            // + ci*2500
  size_t wbase = (((size_t)(b * 52 + i + 1)) * FT_W + (lane + 1)) * 512; // + ci
  int cbeg = cq * 128 + wave * 8;
#pragma unroll
  for (int k = 0; k < 4; ++k) {
    int c0 = cbeg + k * 32;
    __align__(16) unsigned short tmp[8];
#pragma unroll
    for (int t = 0; t < 8; ++t) tmp[t] = f2bf(feat[rbase + (size_t)(c0 + t) * 2500]);
    *(uint4*)(featT + wbase + c0) = *(const uint4*)tmp;
  }
}

// ---------- 2a. compose partials: part[cz][co][kmem] = sum_{c in chunk} whead[co][c]*w1[c][kmem]
__global__ __launch_bounds__(128) void k_weff1(const float* __restrict__ w1,
                                               const float* __restrict__ wc,
                                               const float* __restrict__ wb,
                                               float* __restrict__ part) {
  __shared__ float sW[48][64];
  const int t = threadIdx.x;
  const int kmem = blockIdx.x * 128 + t;   // w1 inner index: ci*9+tap
  const int cz = blockIdx.y;
#pragma unroll
  for (int q = 0; q < 24; ++q) {
    int idx = t + q * 128;                 // < 3072
    int co = idx >> 6, cl = idx & 63;
    int c = cz * 64 + cl;
    float v = 0.f;
    if (co < 9) v = wc[co * 512 + c];
    else if (co < 45) v = wb[(co - 9) * 512 + c];
    sW[co][cl] = v;
  }
  __syncthreads();
  float acc[48];
#pragma unroll
  for (int co = 0; co < 48; ++co) acc[co] = 0.f;
  const float* w1p = w1 + (size_t)(cz * 64) * 4608 + kmem;
  for (int c4 = 0; c4 < 64; c4 += 4) {
    float f0 = w1p[(size_t)(c4 + 0) * 4608];
    float f1 = w1p[(size_t)(c4 + 1) * 4608];
    float f2 = w1p[(size_t)(c4 + 2) * 4608];
    float f3 = w1p[(size_t)(c4 + 3) * 4608];
#pragma unroll
    for (int co = 0; co < 48; ++co) {
      float4 wv = *(const float4*)&sW[co][c4];
      acc[co] += wv.x * f0 + wv.y * f1 + wv.z * f2 + wv.w * f3;
    }
  }
  float* dst = part + (size_t)cz * 221184 + kmem;
#pragma unroll
  for (int co = 0; co < 48; ++co) dst[(size_t)co * 4608] = acc[co];
}

// ---------- 2b. reduce partials + permute kmem->kout + cast bf16 ----------
__global__ __launch_bounds__(256) void k_weff2(const float* __restrict__ part,
                                               unsigned short* __restrict__ wefft) {
  int idx = blockIdx.x * 256 + threadIdx.x;   // < 221184 = 48*4608
  int co = idx / 4608;
  int ko = idx - co * 4608;                   // kout = tap*512+ci
  int tap = ko >> 9, ci = ko & 511;
  int kmem = ci * 9 + tap;
  const float* p = part + (size_t)co * 4608 + kmem;
  float s = 0.f;
#pragma unroll
  for (int cz = 0; cz < 8; ++cz) s += p[(size_t)cz * 221184];
  wefft[idx] = f2bf(s);
}

// ---------- 2c. bias_eff[co] = b_head[co] + whead[co]·b1 ----------
__global__ __launch_bounds__(64) void k_bias(const float* __restrict__ wc,
                                             const float* __restrict__ wb,
                                             const float* __restrict__ b1,
                                             const float* __restrict__ bc,
                                             const float* __restrict__ bbx,
                                             float* __restrict__ bias_eff) {
  int co = blockIdx.x, l = threadIdx.x;
  float s = 0.f;
#pragma unroll
  for (int q = 0; q < 8; ++q) {
    int c = q * 64 + l;
    float wv = co < 9 ? wc[co * 512 + c] : (co < 45 ? wb[(co - 9) * 512 + c] : 0.f);
    s += wv * b1[c];
  }
  for (int o = 32; o; o >>= 1) s += __shfl_down(s, o, 64);
  if (l == 0)
    bias_eff[co] = s + (co < 9 ? bc[co] : (co < 45 ? bbx[co - 9] : 0.f));
}

// ---------- 3. IoU pass: full tensor + per-(b,gt) max ----------
__global__ __launch_bounds__(256) void k_iou(const float* __restrict__ gt_boxes,
                                             float* __restrict__ ioub,
                                             unsigned* __restrict__ mx) {
  int b = blockIdx.y;
  int n = blockIdx.x * 256 + threadIdx.x;
  float lm[16];
#pragma unroll
  for (int m = 0; m < 16; ++m) lm[m] = 0.f;
  if (n < 22500) {
    float ax1, ay1, ax2, ay2;
    anchor_of(n, ax1, ay1, ax2, ay2);
    float aarea = (ax2 - ax1) * (ay2 - ay1);
    float* dst = ioub + ((size_t)b * 22500 + n) * 16;
#pragma unroll
    for (int m = 0; m < 16; ++m) {
      const float* g = gt_boxes + (b * 16 + m) * 4;
      float gx1 = g[0] * 0.0625f, gy1 = g[1] * 0.0625f;
      float gx2 = g[2] * 0.0625f, gy2 = g[3] * 0.0625f;
      float ix1 = fmaxf(ax1, gx1), iy1 = fmaxf(ay1, gy1);
      float ix2 = fminf(ax2, gx2), iy2 = fminf(ay2, gy2);
      float inter = fmaxf(ix2 - ix1, 0.f) * fmaxf(iy2 - iy1, 0.f);
      float garea = (gx2 - gx1) * (gy2 - gy1);
      float iou = inter / (aarea + garea - inter + 1e-8f);
      dst[m] = iou;
      lm[m] = iou;
    }
  }
  __shared__ float red[4][16];
#pragma unroll
  for (int m = 0; m < 16; ++m) {
    float v = lm[m];
    for (int o = 32; o; o >>= 1) v = fmaxf(v, __shfl_down(v, o, 64));
    if ((threadIdx.x & 63) == 0) red[threadIdx.x >> 6][m] = v;
  }
  __syncthreads();
  if (threadIdx.x < 16) {
    float v = fmaxf(fmaxf(red[0][threadIdx.x], red[1][threadIdx.x]),
                    fmaxf(red[2][threadIdx.x], red[3][threadIdx.x]));
    atomicMax(mx + b * 16 + threadIdx.x, __float_as_uint(v));
  }
}

// ---------- 4. fused conv+head implicit GEMM ----------
// C[m][co<48] partial over K-slice kz: 48x256 tile, BK=32, K=1152 per kz.
// LDS kq swizzle: phys_kq = (log_kq + (row>>1)) & 3  -> 2-way banks (free).
__global__ __launch_bounds__(256, 4) void k_conv(const unsigned short* __restrict__ featT,
                                                 const unsigned short* __restrict__ wefft,
                                                 float* __restrict__ ohp) {
  __shared__ __align__(16) unsigned short sA[48 * 32];
  __shared__ __align__(16) unsigned short sB[256 * 32];
  const int tid = threadIdx.x, lane = tid & 63, wave = tid >> 6;
  const int m0 = blockIdx.x * 256;
  const int kz = blockIdx.y;

  // A staging: threads 0..191, chunk row=tid>>2 (co), phys kq=tid&3
  const char* gA = (const char*)wefft;
  if (tid < 192) {
    int row = tid >> 2;
    int kql = ((tid & 3) - ((tid >> 3) & 3)) & 3;
    gA = (const char*)(wefft + (size_t)row * 4608 + kz * 1152 + kql * 8);
  }
  // B staging: 4 issues; issue i row = m0 + i*64 + (tid>>2), phys kq = lane&3
  const char* gB[4];
  {
    int kql = ((lane & 3) - ((lane >> 3) & 3)) & 3;
#pragma unroll
    for (int i = 0; i < 4; ++i) {
      int mm = m0 + i * 64 + (tid >> 2);
      mm = min(mm, 39999);
      int r = mm / 50, j = mm - r * 50;
      int bb = r / 50, ii = r - bb * 50;
      gB[i] = (const char*)(featT + ((size_t)((bb * 52 + ii) * FT_W + j)) * 512 + kql * 8);
    }
  }
  char* dA  = (char*)sA + wave * 1024;
  char* dB0 = (char*)sB + wave * 1024;

  const int kqf = ((lane >> 4) + ((lane & 15) >> 1)) & 3;
  const char* fA = (const char*)sA + (lane & 15) * 64 + kqf * 16;
  const char* fB = (const char*)sB + (wave * 64 + (lane & 15)) * 64 + kqf * 16;

  f32x4 acc[3][4] = {};

  for (int kt = 0; kt < 36; ++kt) {
    int k0 = kz * 1152 + kt * 32;
    int tap = k0 >> 9;
    int ci0 = k0 & 511;
    int th = tap / 3, tw = tap - th * 3;
    size_t offB = ((size_t)(th * FT_W + tw) * 512 + ci0) * 2;
    if (wave < 3) gl_lds16(gA + (size_t)kt * 64, dA);
    gl_lds16(gB[0] + offB, dB0);
    gl_lds16(gB[1] + offB, dB0 + 4096);
    gl_lds16(gB[2] + offB, dB0 + 8192);
    gl_lds16(gB[3] + offB, dB0 + 12288);
    __builtin_amdgcn_s_waitcnt(0);   // drain vmcnt (async LDS writes) before barrier
    __syncthreads();
    bf16x8 a[3], bv[4];
#pragma unroll
    for (int mi = 0; mi < 3; ++mi) a[mi] = *(const bf16x8*)(fA + mi * 1024);
#pragma unroll
    for (int ni = 0; ni < 4; ++ni) bv[ni] = *(const bf16x8*)(fB + ni * 1024);
#pragma unroll
    for (int mi = 0; mi < 3; ++mi)
#pragma unroll
      for (int ni = 0; ni < 4; ++ni)
        acc[mi][ni] = __builtin_amdgcn_mfma_f32_16x16x32_bf16(a[mi], bv[ni], acc[mi][ni], 0, 0, 0);
    __syncthreads();
  }

  // epilogue: D col = m (lane&15), row = co quad. float4 per (mi,ni).
#pragma unroll
  for (int ni = 0; ni < 4; ++ni) {
    int m = m0 + wave * 64 + ni * 16 + (lane & 15);
    if (m >= 40000) continue;
    float* dst = ohp + ((size_t)kz * 40000 + m) * 48 + (lane >> 4) * 4;
#pragma unroll
    for (int mi = 0; mi < 3; ++mi)
      *(f32x4*)(dst + mi * 16) = acc[mi][ni];
  }
}

// ---------- 5. loss pass: masks, loss partial sums, proposals ----------
__global__ __launch_bounds__(256) void k_loss(const float* __restrict__ gt_boxes,
                                              const float* __restrict__ ioub,
                                              const unsigned* __restrict__ mxbuf,
                                              const float* __restrict__ ohp,
                                              const float* __restrict__ bias_eff,
                                              float* __restrict__ accum,
                                              float* __restrict__ dout) {
  int b = blockIdx.y;
  int n = blockIdx.x * 256 + threadIdx.x;
  float s_np = 0.f, s_reg = 0.f, s_pos = 0.f, s_nc = 0.f, s_nl = 0.f;
  if (n < 22500) {
    float ax1, ay1, ax2, ay2;
    anchor_of(n, ax1, ay1, ax2, ay2);
    float acx = (ax1 + ax2) * 0.5f, acy = (ay1 + ay2) * 0.5f;
    float aw = fmaxf(ax2 - ax1, 1e-6f), ah = fmaxf(ay2 - ay1, 1e-6f);
    int ii = n / 450, rem = n - ii * 450, jj = rem / 9, a = rem - jj * 9;
    size_t mrow = (size_t)b * 2500 + ii * 50 + jj;
    float logit = bias_eff[a];
    float p0 = bias_eff[9 + a * 4], p1 = bias_eff[10 + a * 4];
    float p2 = bias_eff[11 + a * 4], p3 = bias_eff[12 + a * 4];
#pragma unroll
    for (int kz = 0; kz < 4; ++kz) {
      const float* rp = ohp + ((size_t)kz * 40000 + mrow) * 48;
      logit += rp[a];
      p0 += rp[9 + a * 4]; p1 += rp[10 + a * 4];
      p2 += rp[11 + a * 4]; p3 += rp[12 + a * 4];
    }
    const float* ioup = ioub + ((size_t)b * 22500 + n) * 16;
    int npos = 0;
    bool allneg = true;
#pragma unroll
    for (int m = 0; m < 16; ++m) {
      float iou = ioup[m];
      float mxv = __uint_as_float(mxbuf[b * 16 + m]);
      bool pos = ((iou == mxv) && (mxv > 0.f)) || (iou > 0.7f);
      if (iou >= 0.3f) allneg = false;
      if (pos) {
        ++npos;
        const float* g = gt_boxes + (b * 16 + m) * 4;
        float gx1 = g[0] * 0.0625f, gy1 = g[1] * 0.0625f;
        float gx2 = g[2] * 0.0625f, gy2 = g[3] * 0.0625f;
        float gcx = (gx1 + gx2) * 0.5f, gcy = (gy1 + gy2) * 0.5f;
        float gw = fmaxf(gx2 - gx1, 1e-6f), gh = fmaxf(gy2 - gy1, 1e-6f);
        float tx = (gcx - acx) / aw, ty = (gcy - acy) / ah;
        float twv = logf(gw / aw), thv = logf(gh / ah);
        s_reg += sl1(tx - p0) + sl1(ty - p1) + sl1(twv - p2) + sl1(thv - p3);
      }
    }
    s_np = (float)npos;
    s_pos = (float)npos * softplus_f(-logit);
    if (allneg) { s_nc = 1.f; s_nl = softplus_f(logit); }
    float pcx = acx + p0 * aw, pcy = acy + p1 * ah;
    float pw = aw * expf(p2), ph = ah * expf(p3);
    float* o = dout + 1 + ((size_t)b * 22500 + n) * 4;
    o[0] = pcx - pw * 0.5f;
    o[1] = pcy - ph * 0.5f;
    o[2] = pcx + pw * 0.5f;
    o[3] = pcy + ph * 0.5f;
  }
  float vals[5] = {s_np, s_reg, s_pos, s_nc, s_nl};
  __shared__ float red[4][5];
#pragma unroll
  for (int q = 0; q < 5; ++q) {
    float v = vals[q];
    for (int o = 32; o; o >>= 1) v += __shfl_down(v, o, 64);
    if ((threadIdx.x & 63) == 0) red[threadIdx.x >> 6][q] = v;
  }
  __syncthreads();
  if (threadIdx.x < 5) {
    float v = red[0][threadIdx.x] + red[1][threadIdx.x] + red[2][threadIdx.x] + red[3][threadIdx.x];
    atomicAdd(accum + threadIdx.x, v);
  }
}

// ---------- 6. finalize ----------
__global__ void k_fin(const float* __restrict__ accum, float* __restrict__ dout) {
  if (threadIdx.x == 0 && blockIdx.x == 0) {
    float np = fmaxf(accum[0], 1.f);
    float nn = fmaxf(accum[3], 1.f);
    float loss = 0.5f * (accum[2] / np + accum[4] / nn) + 5.f * (accum[1] / (4.f * np));
    dout[0] = loss;
  }
}

// ---------- launch ----------
extern "C" void kernel_launch(void* const* d_in, const int* in_sizes, int n_in,
                              void* d_out, int out_size, void* d_ws, size_t ws_size,
                              hipStream_t stream) {
  const float* features = (const float*)d_in[0];
  const float* gt_boxes = (const float*)d_in[1];
  const float* w1    = (const float*)d_in[2];
  const float* b1    = (const float*)d_in[3];
  const float* w_cls = (const float*)d_in[4];
  const float* b_cls = (const float*)d_in[5];
  const float* w_box = (const float*)d_in[6];
  const float* b_box = (const float*)d_in[7];
  float* out = (float*)d_out;
  char* ws = (char*)d_ws;

  // ws layout (featT [16][52][52][512] bf16 = 44,302,336 B)
  unsigned short* featT = (unsigned short*)(ws);                // 44,302,336 B
  unsigned short* wefft = (unsigned short*)(ws + 44302336);     //    442,368 B
  float*          wpart = (float*)(ws + 44744704);              //  7,077,888 B
  float*          ohp   = (float*)(ws + 51822592);              // 30,720,000 B
  float*          ioub  = (float*)(ws + 82542592);              // 23,040,000 B
  float*          beff  = (float*)(ws + 105582592);             //        192 B
  unsigned*       mx    = (unsigned*)(ws + 105582784);          //      1,024 B
  float*          accum = (float*)(ws + 105583808);             //         32 B

  hipMemsetAsync(featT, 0, 44302336, stream);                   // zero incl. borders
  hipMemsetAsync(ws + 105582784, 0, 1056, stream);              // maxiou + accums

  k_featT<<<dim3(800, 4), 256, 0, stream>>>(features, featT);
  k_weff1<<<dim3(36, 8), 128, 0, stream>>>(w1, w_cls, w_box, wpart);
  k_weff2<<<864, 256, 0, stream>>>(wpart, wefft);
  k_bias<<<48, 64, 0, stream>>>(w_cls, w_box, b1, b_cls, b_box, beff);
  k_iou<<<dim3(88, 16), 256, 0, stream>>>(gt_boxes, ioub, mx);
  k_conv<<<dim3(157, 4), 256, 0, stream>>>(featT, wefft, ohp);
  k_loss<<<dim3(88, 16), 256, 0, stream>>>(gt_boxes, ioub, mx, ohp, beff, accum, out);
  k_fin<<<1, 64, 0, stream>>>(accum, out);
}

// Round 5
// 296.925 us; speedup vs baseline: 2.0639x; 1.0741x over previous
//
#include <hip/hip_runtime.h>
#include <hip/hip_bf16.h>
#include <stdint.h>

using bf16x8 = __attribute__((ext_vector_type(8))) __bf16;
using f32x4  = __attribute__((ext_vector_type(4))) float;

// featT2 layout: [16][52][52] positions (row/col 0,51 = zero borders, full memset
// each call — R3 showed partial init diverges under the harness re-poison), each
// position = 16 ci-chunks x 80 B (32 bf16 data + 16 B pad). Pad gives 20-bank
// stride for conflict-free ds_read_b128 fragments.
#define FT_POS_B 1280
// W2 layout: [ci-chunk 16][tap 9][co 48][80 B record]
#define W2_CHUNK_B 34560

// ---------- helpers ----------
__device__ __forceinline__ unsigned short f2bf(float f) {
  union { float f; unsigned u; } x; x.f = f;
  unsigned r = x.u + 0x7fffu + ((x.u >> 16) & 1u);   // RNE
  return (unsigned short)(r >> 16);
}

__device__ __forceinline__ void gl_lds16(const void* g, void* l) {
  __builtin_amdgcn_global_load_lds(
      (const __attribute__((address_space(1))) void*)g,
      (__attribute__((address_space(3))) void*)l, 16, 0, 0);
}

__device__ __forceinline__ float sl1(float d) {
  float ad = fabsf(d);
  return ad < 1.f ? 0.5f * d * d : ad - 0.5f;
}
__device__ __forceinline__ float softplus_f(float x) {
  return fmaxf(x, 0.f) + log1pf(expf(-fabsf(x)));
}

// strict-fp anchor + IoU: identical bits in k_iou and k_loss (no contraction
// possible through __f*_rn intrinsics) so the (iou == max) test is exact.
__device__ __forceinline__ void anchor_strict(int n, float& ax1, float& ay1,
                                              float& ax2, float& ay2) {
  int ii = n / 450;
  int rem = n - ii * 450;
  int jj = rem / 9;
  int a  = rem - jj * 9;
  const float SC[3] = {2.f, 4.f, 6.f};
  const float RA[3] = {0.5f, 1.f, 1.5f};
  float w = __fmul_rn(SC[a % 3], RA[a / 3]);
  float h = SC[a % 3];
  float cx = __fadd_rn((float)ii, 0.5f);
  float cy = __fadd_rn((float)jj, 0.5f);
  float wh = __fmul_rn(w, 0.5f), hh = __fmul_rn(h, 0.5f);
  ax1 = fminf(fmaxf(__fsub_rn(cx, wh), 0.f), 50.f);
  ax2 = fminf(fmaxf(__fadd_rn(cx, wh), 0.f), 50.f);
  ay1 = fminf(fmaxf(__fsub_rn(cy, hh), 0.f), 50.f);
  ay2 = fminf(fmaxf(__fadd_rn(cy, hh), 0.f), 50.f);
}
__device__ __forceinline__ float iou_strict(float ax1, float ay1, float ax2, float ay2,
                                            float aarea, const float* __restrict__ g) {
  float gx1 = __fmul_rn(g[0], 0.0625f), gy1 = __fmul_rn(g[1], 0.0625f);
  float gx2 = __fmul_rn(g[2], 0.0625f), gy2 = __fmul_rn(g[3], 0.0625f);
  float ix1 = fmaxf(ax1, gx1), iy1 = fmaxf(ay1, gy1);
  float ix2 = fminf(ax2, gx2), iy2 = fminf(ay2, gy2);
  float inter = __fmul_rn(fmaxf(__fsub_rn(ix2, ix1), 0.f),
                          fmaxf(__fsub_rn(iy2, iy1), 0.f));
  float garea = __fmul_rn(__fsub_rn(gx2, gx1), __fsub_rn(gy2, gy1));
  float denom = __fadd_rn(__fsub_rn(__fadd_rn(aarea, garea), inter), 1e-8f);
  return __fdiv_rn(inter, denom);
}

// ---------- 1. features NCHW fp32 -> padded-record NHWC bf16 ----------
__global__ __launch_bounds__(256) void k_featT(const float* __restrict__ feat,
                                               char* __restrict__ featT2) {
  int row = blockIdx.x;            // b*50 + i
  int cq  = blockIdx.y;            // 0..7, 64 channels each
  int b = row / 50, i = row - b * 50;
  int w = threadIdx.x >> 6, lane = threadIdx.x & 63;
  if (lane >= 50) return;
  size_t rbase = (size_t)b * 1280000 + (size_t)i * 50 + lane;   // + ci*2500
  char* wpos = featT2 + (size_t)((b * 52 + i + 1) * 52 + (lane + 1)) * FT_POS_B;
#pragma unroll
  for (int k = 0; k < 2; ++k) {
    int c0 = cq * 64 + w * 8 + k * 32;
    __align__(16) unsigned short tmp[8];
#pragma unroll
    for (int t = 0; t < 8; ++t) tmp[t] = f2bf(feat[rbase + (size_t)(c0 + t) * 2500]);
    *(uint4*)(wpos + (c0 >> 5) * 80 + (c0 & 31) * 2) = *(const uint4*)tmp;
  }
}

// ---------- 2a. compose partials: part[cz][co][kmem], kmem = ci*9+tap ----------
__global__ __launch_bounds__(128) void k_weff1(const float* __restrict__ w1,
                                               const float* __restrict__ wc,
                                               const float* __restrict__ wb,
                                               float* __restrict__ part) {
  __shared__ float sW[48][64];
  const int t = threadIdx.x;
  const int kmem = blockIdx.x * 128 + t;
  const int cz = blockIdx.y;
#pragma unroll
  for (int q = 0; q < 24; ++q) {
    int idx = t + q * 128;
    int co = idx >> 6, cl = idx & 63;
    int c = cz * 64 + cl;
    float v = 0.f;
    if (co < 9) v = wc[co * 512 + c];
    else if (co < 45) v = wb[(co - 9) * 512 + c];
    sW[co][cl] = v;
  }
  __syncthreads();
  float acc[48];
#pragma unroll
  for (int co = 0; co < 48; ++co) acc[co] = 0.f;
  const float* w1p = w1 + (size_t)(cz * 64) * 4608 + kmem;
  for (int c4 = 0; c4 < 64; c4 += 4) {
    float f0 = w1p[(size_t)(c4 + 0) * 4608];
    float f1 = w1p[(size_t)(c4 + 1) * 4608];
    float f2 = w1p[(size_t)(c4 + 2) * 4608];
    float f3 = w1p[(size_t)(c4 + 3) * 4608];
#pragma unroll
    for (int co = 0; co < 48; ++co) {
      float4 wv = *(const float4*)&sW[co][c4];
      acc[co] += wv.x * f0 + wv.y * f1 + wv.z * f2 + wv.w * f3;
    }
  }
  float* dst = part + (size_t)cz * 221184 + kmem;
#pragma unroll
  for (int co = 0; co < 48; ++co) dst[(size_t)co * 4608] = acc[co];
}

// ---------- 2b. reduce partials -> W2 padded records (bf16) ----------
__global__ __launch_bounds__(256) void k_weff2(const float* __restrict__ part,
                                               unsigned short* __restrict__ w2) {
  int idx = blockIdx.x * 256 + threadIdx.x;   // < 276480 = 16*9*48*40
  int c = idx / 17280;  int r = idx - c * 17280;
  int tap = r / 1920;   int r2 = r - tap * 1920;
  int co = r2 / 40;     int e = r2 - co * 40;
  float s = 0.f;
  if (e < 32) {
    int ci = c * 32 + e;
    const float* p = part + (size_t)co * 4608 + ci * 9 + tap;
#pragma unroll
    for (int cz = 0; cz < 8; ++cz) s += p[(size_t)cz * 221184];
  }
  w2[idx] = f2bf(s);
}

// ---------- 2c. bias_eff[co] = b_head[co] + whead[co]·b1 ----------
__global__ __launch_bounds__(64) void k_bias(const float* __restrict__ wc,
                                             const float* __restrict__ wb,
                                             const float* __restrict__ b1,
                                             const float* __restrict__ bc,
                                             const float* __restrict__ bbx,
                                             float* __restrict__ bias_eff) {
  int co = blockIdx.x, l = threadIdx.x;
  float s = 0.f;
#pragma unroll
  for (int q = 0; q < 8; ++q) {
    int c = q * 64 + l;
    float wv = co < 9 ? wc[co * 512 + c] : (co < 45 ? wb[(co - 9) * 512 + c] : 0.f);
    s += wv * b1[c];
  }
  for (int o = 32; o; o >>= 1) s += __shfl_down(s, o, 64);
  if (l == 0)
    bias_eff[co] = s + (co < 9 ? bc[co] : (co < 45 ? bbx[co - 9] : 0.f));
}

// ---------- 3. per-(b,gt) max IoU (no ioub store; k_loss recomputes) ----------
__global__ __launch_bounds__(256) void k_iou(const float* __restrict__ gt_boxes,
                                             unsigned* __restrict__ mx) {
  int b = blockIdx.y;
  int n = blockIdx.x * 256 + threadIdx.x;
  float lm[16];
#pragma unroll
  for (int m = 0; m < 16; ++m) lm[m] = 0.f;
  if (n < 22500) {
    float ax1, ay1, ax2, ay2;
    anchor_strict(n, ax1, ay1, ax2, ay2);
    float aarea = __fmul_rn(__fsub_rn(ax2, ax1), __fsub_rn(ay2, ay1));
#pragma unroll
    for (int m = 0; m < 16; ++m)
      lm[m] = iou_strict(ax1, ay1, ax2, ay2, aarea, gt_boxes + (b * 16 + m) * 4);
  }
  __shared__ float red[4][16];
#pragma unroll
  for (int m = 0; m < 16; ++m) {
    float v = lm[m];
    for (int o = 32; o; o >>= 1) v = fmaxf(v, __shfl_down(v, o, 64));
    if ((threadIdx.x & 63) == 0) red[threadIdx.x >> 6][m] = v;
  }
  __syncthreads();
  if (threadIdx.x < 16) {
    float v = fmaxf(fmaxf(red[0][threadIdx.x], red[1][threadIdx.x]),
                    fmaxf(red[2][threadIdx.x], red[3][threadIdx.x]));
    atomicMax(mx + b * 16 + threadIdx.x, __float_as_uint(v));
  }
}

// ---------- 4. direct conv+head: spatial tiles, all 9 taps from LDS ----------
// Block = one image x one ~13x13 tile. 16 ci-chunks, double-buffered staging.
// Per wave: 3 co-frags x 3 m-frags of mfma 16x16x32 per tap.
__global__ __launch_bounds__(256) void k_conv(const char* __restrict__ featT2,
                                              const char* __restrict__ w2,
                                              const float* __restrict__ beff,
                                              float* __restrict__ oh) {
  __shared__ __align__(16) char sF[2][19456];   // 225*80=18000 used; 18*1024 staged
  __shared__ __align__(16) char sA[2][34816];   // 9*48*80=34560; 34*1024 staged
  const int tid = threadIdx.x, lane = tid & 63, w = tid >> 6;
  const int bx = blockIdx.x;
  const int b = bx >> 4, tl = bx & 15, tr = tl >> 2, tc = tl & 3;
  const int i0 = tr * 13 - (tr == 3 ? 1 : 0);   // {0,13,26,38}
  const int TI = (tr >= 2) ? 12 : 13;
  const int j0 = tc * 13 - (tc == 3 ? 1 : 0);
  const int TJ = (tc >= 2) ? 12 : 13;
  const int TJ2 = TJ + 2;
  const int mcount = TI * TJ;
  const int pieces = (TI + 2) * TJ2 * 5;        // 16B pieces per chunk

  // sF staging sources: instr s = w*5+k (s<18), piece pi = s*64+lane
  const char* srcF[5];
#pragma unroll
  for (int k = 0; k < 5; ++k) {
    int s = w * 5 + k;
    int pi = s * 64 + lane;
    if (pi >= pieces) pi = pieces - 1;
    int pos = pi / 5, pc = pi - pos * 5;
    int hi = pos / TJ2, hj = pos - hi * TJ2;
    srcF[k] = featT2 + (size_t)((b * 52 + i0 + hi) * 52 + (j0 + hj)) * FT_POS_B + pc * 16;
  }
  // B-fragment LDS bases: halo idx = (di+dr)*TJ2 + (dj+dc), dr=dc=0 base here
  int idxB[3];
#pragma unroll
  for (int bf = 0; bf < 3; ++bf) {
    int p = (w * 3 + bf) * 16 + (lane & 15);
    if (p >= mcount) p = mcount - 1;
    int di = p / TJ, dj = p - di * TJ;
    idxB[bf] = (di * TJ2 + dj) * 80 + (lane >> 4) * 16;
  }
  const int aoff = (lane & 15) * 80 + (lane >> 4) * 16;
  int toff[9];
#pragma unroll
  for (int tp = 0; tp < 9; ++tp) toff[tp] = ((tp / 3) * TJ2 + (tp % 3)) * 80;

  f32x4 acc[3][3] = {};

  auto stage = [&](int c, int pb) {
#pragma unroll
    for (int k = 0; k < 5; ++k) {
      int s = w * 5 + k;
      if (s < 18) gl_lds16(srcF[k] + (size_t)c * 80, sF[pb] + s * 1024);
    }
#pragma unroll
    for (int k = 0; k < 9; ++k) {
      int s = w + 4 * k;
      if (s < 34)
        gl_lds16(w2 + (size_t)c * W2_CHUNK_B + s * 1024 + lane * 16, sA[pb] + s * 1024);
    }
  };

  stage(0, 0);
  __builtin_amdgcn_s_waitcnt(0);
  __syncthreads();

  for (int c = 0; c < 16; ++c) {
    int pb = c & 1;
    if (c < 15) stage(c + 1, pb ^ 1);
    const char* fA = sA[pb];
    const char* fB = sF[pb];
#pragma unroll
    for (int tp = 0; tp < 9; ++tp) {
      bf16x8 av[3], bv[3];
#pragma unroll
      for (int cf = 0; cf < 3; ++cf)
        av[cf] = *(const bf16x8*)(fA + tp * 3840 + cf * 1280 + aoff);
#pragma unroll
      for (int bf = 0; bf < 3; ++bf)
        bv[bf] = *(const bf16x8*)(fB + idxB[bf] + toff[tp]);
#pragma unroll
      for (int cf = 0; cf < 3; ++cf)
#pragma unroll
        for (int bf = 0; bf < 3; ++bf)
          acc[cf][bf] = __builtin_amdgcn_mfma_f32_16x16x32_bf16(av[cf], bv[bf], acc[cf][bf], 0, 0, 0);
    }
    __builtin_amdgcn_s_waitcnt(0);
    __syncthreads();
  }

  f32x4 bias[3];
#pragma unroll
  for (int cf = 0; cf < 3; ++cf)
    bias[cf] = *(const f32x4*)(beff + cf * 16 + (lane >> 4) * 4);
#pragma unroll
  for (int bf = 0; bf < 3; ++bf) {
    int p = (w * 3 + bf) * 16 + (lane & 15);
    if (p >= mcount) continue;
    int di = p / TJ, dj = p - di * TJ;
    int gm = (b * 50 + i0 + di) * 50 + (j0 + dj);
#pragma unroll
    for (int cf = 0; cf < 3; ++cf) {
      f32x4 v = acc[cf][bf];
#pragma unroll
      for (int r = 0; r < 4; ++r) v[r] += bias[cf][r];
      *(f32x4*)(oh + (size_t)gm * 48 + cf * 16 + (lane >> 4) * 4) = v;
    }
  }
}

// ---------- 5. loss pass: recompute IoU (strict), loss sums, proposals ----------
__global__ __launch_bounds__(256) void k_loss(const float* __restrict__ gt_boxes,
                                              const unsigned* __restrict__ mxbuf,
                                              const float* __restrict__ oh,
                                              float* __restrict__ accum,
                                              float* __restrict__ dout) {
  int b = blockIdx.y;
  int n = blockIdx.x * 256 + threadIdx.x;
  float s_np = 0.f, s_reg = 0.f, s_pos = 0.f, s_nc = 0.f, s_nl = 0.f;
  if (n < 22500) {
    float ax1, ay1, ax2, ay2;
    anchor_strict(n, ax1, ay1, ax2, ay2);
    float aarea = __fmul_rn(__fsub_rn(ax2, ax1), __fsub_rn(ay2, ay1));
    float acx = (ax1 + ax2) * 0.5f, acy = (ay1 + ay2) * 0.5f;
    float aw = fmaxf(ax2 - ax1, 1e-6f), ah = fmaxf(ay2 - ay1, 1e-6f);
    int ii = n / 450, rem = n - ii * 450, jj = rem / 9, a = rem - jj * 9;
    const float* row = oh + ((size_t)(b * 2500 + ii * 50 + jj)) * 48;
    float logit = row[a];
    float p0 = row[9 + a * 4], p1 = row[10 + a * 4];
    float p2 = row[11 + a * 4], p3 = row[12 + a * 4];
    int npos = 0;
    bool allneg = true;
#pragma unroll
    for (int m = 0; m < 16; ++m) {
      const float* g = gt_boxes + (b * 16 + m) * 4;
      float iou = iou_strict(ax1, ay1, ax2, ay2, aarea, g);
      float mxv = __uint_as_float(mxbuf[b * 16 + m]);
      bool pos = ((iou == mxv) && (mxv > 0.f)) || (iou > 0.7f);
      if (iou >= 0.3f) allneg = false;
      if (pos) {
        ++npos;
        float gx1 = g[0] * 0.0625f, gy1 = g[1] * 0.0625f;
        float gx2 = g[2] * 0.0625f, gy2 = g[3] * 0.0625f;
        float gcx = (gx1 + gx2) * 0.5f, gcy = (gy1 + gy2) * 0.5f;
        float gw = fmaxf(gx2 - gx1, 1e-6f), gh = fmaxf(gy2 - gy1, 1e-6f);
        float tx = (gcx - acx) / aw, ty = (gcy - acy) / ah;
        float twv = logf(gw / aw), thv = logf(gh / ah);
        s_reg += sl1(tx - p0) + sl1(ty - p1) + sl1(twv - p2) + sl1(thv - p3);
      }
    }
    s_np = (float)npos;
    s_pos = (float)npos * softplus_f(-logit);
    if (allneg) { s_nc = 1.f; s_nl = softplus_f(logit); }
    float pcx = acx + p0 * aw, pcy = acy + p1 * ah;
    float pw = aw * expf(p2), ph = ah * expf(p3);
    float* o = dout + 1 + ((size_t)b * 22500 + n) * 4;
    o[0] = pcx - pw * 0.5f;
    o[1] = pcy - ph * 0.5f;
    o[2] = pcx + pw * 0.5f;
    o[3] = pcy + ph * 0.5f;
  }
  float vals[5] = {s_np, s_reg, s_pos, s_nc, s_nl};
  __shared__ float red[4][5];
#pragma unroll
  for (int q = 0; q < 5; ++q) {
    float v = vals[q];
    for (int o = 32; o; o >>= 1) v += __shfl_down(v, o, 64);
    if ((threadIdx.x & 63) == 0) red[threadIdx.x >> 6][q] = v;
  }
  __syncthreads();
  if (threadIdx.x < 5) {
    float v = red[0][threadIdx.x] + red[1][threadIdx.x] +
              red[2][threadIdx.x] + red[3][threadIdx.x];
    atomicAdd(accum + threadIdx.x, v);
  }
}

// ---------- 6. finalize ----------
__global__ void k_fin(const float* __restrict__ accum, float* __restrict__ dout) {
  if (threadIdx.x == 0 && blockIdx.x == 0) {
    float np = fmaxf(accum[0], 1.f);
    float nn = fmaxf(accum[3], 1.f);
    float loss = 0.5f * (accum[2] / np + accum[4] / nn) + 5.f * (accum[1] / (4.f * np));
    dout[0] = loss;
  }
}

// ---------- launch ----------
extern "C" void kernel_launch(void* const* d_in, const int* in_sizes, int n_in,
                              void* d_out, int out_size, void* d_ws, size_t ws_size,
                              hipStream_t stream) {
  const float* features = (const float*)d_in[0];
  const float* gt_boxes = (const float*)d_in[1];
  const float* w1    = (const float*)d_in[2];
  const float* b1    = (const float*)d_in[3];
  const float* w_cls = (const float*)d_in[4];
  const float* b_cls = (const float*)d_in[5];
  const float* w_box = (const float*)d_in[6];
  const float* b_box = (const float*)d_in[7];
  float* out = (float*)d_out;
  char* ws = (char*)d_ws;

  // ws layout
  char*           featT2 = ws;                                  // 55,377,920 B
  unsigned short* w2     = (unsigned short*)(ws + 55377920);    //    552,960 B
  float*          wpart  = (float*)(ws + 55930880);             //  7,077,888 B
  float*          oh     = (float*)(ws + 63008768);             //  7,680,000 B
  float*          beff   = (float*)(ws + 70688768);             //        192 B
  unsigned*       mx     = (unsigned*)(ws + 70688960);          //      1,024 B
  float*          accum  = (float*)(ws + 70689984);             //         32 B

  hipMemsetAsync(featT2, 0, 55377920, stream);                  // zero incl. borders
  hipMemsetAsync(ws + 70688960, 0, 1056, stream);               // maxiou + accums

  k_featT<<<dim3(800, 8), 256, 0, stream>>>(features, featT2);
  k_weff1<<<dim3(36, 8), 128, 0, stream>>>(w1, w_cls, w_box, wpart);
  k_weff2<<<1080, 256, 0, stream>>>(wpart, w2);
  k_bias<<<48, 64, 0, stream>>>(w_cls, w_box, b1, b_cls, b_box, beff);
  k_iou<<<dim3(88, 16), 256, 0, stream>>>(gt_boxes, mx);
  k_conv<<<256, 256, 0, stream>>>(featT2, (const char*)w2, beff, oh);
  k_loss<<<dim3(88, 16), 256, 0, stream>>>(gt_boxes, mx, oh, accum, out);
  k_fin<<<1, 64, 0, stream>>>(accum, out);
}

// Round 6
// 279.946 us; speedup vs baseline: 2.1891x; 1.0607x over previous
//
#include <hip/hip_runtime.h>
#include <hip/hip_bf16.h>
#include <stdint.h>

using bf16x8 = __attribute__((ext_vector_type(8))) __bf16;
using f32x4  = __attribute__((ext_vector_type(4))) float;

// featT2 layout: [16][52][52] positions (row/col 0,51 = zero borders), each
// position = 16 ci-chunks x 80 B (32 bf16 data + 16 B pad). Pad bytes are NEVER
// read (k_conv fragment offsets < 64 within a record) so they may stay poison;
// all DATA bytes are written every call by k_featT (interior tiles + border
// tile 40) — no memset needed.
#define FT_POS_B 1280
// W2 layout: [ci-chunk 16][tap 9][co 48][80 B record]
#define W2_CHUNK_B 34560

// ---------- helpers ----------
__device__ __forceinline__ unsigned short f2bf(float f) {
  union { float f; unsigned u; } x; x.f = f;
  unsigned r = x.u + 0x7fffu + ((x.u >> 16) & 1u);   // RNE
  return (unsigned short)(r >> 16);
}

__device__ __forceinline__ void gl_lds16(const void* g, void* l) {
  __builtin_amdgcn_global_load_lds(
      (const __attribute__((address_space(1))) void*)g,
      (__attribute__((address_space(3))) void*)l, 16, 0, 0);
}

__device__ __forceinline__ float sl1(float d) {
  float ad = fabsf(d);
  return ad < 1.f ? 0.5f * d * d : ad - 0.5f;
}
__device__ __forceinline__ float softplus_f(float x) {
  return fmaxf(x, 0.f) + log1pf(expf(-fabsf(x)));
}

// strict-fp anchor + IoU: identical bits in k_iou and k_loss (no contraction
// possible through __f*_rn intrinsics) so the (iou == max) test is exact.
__device__ __forceinline__ void anchor_strict(int n, float& ax1, float& ay1,
                                              float& ax2, float& ay2) {
  int ii = n / 450;
  int rem = n - ii * 450;
  int jj = rem / 9;
  int a  = rem - jj * 9;
  const float SC[3] = {2.f, 4.f, 6.f};
  const float RA[3] = {0.5f, 1.f, 1.5f};
  float w = __fmul_rn(SC[a % 3], RA[a / 3]);
  float h = SC[a % 3];
  float cx = __fadd_rn((float)ii, 0.5f);
  float cy = __fadd_rn((float)jj, 0.5f);
  float wh = __fmul_rn(w, 0.5f), hh = __fmul_rn(h, 0.5f);
  ax1 = fminf(fmaxf(__fsub_rn(cx, wh), 0.f), 50.f);
  ax2 = fminf(fmaxf(__fadd_rn(cx, wh), 0.f), 50.f);
  ay1 = fminf(fmaxf(__fsub_rn(cy, hh), 0.f), 50.f);
  ay2 = fminf(fmaxf(__fadd_rn(cy, hh), 0.f), 50.f);
}
__device__ __forceinline__ float iou_strict(float ax1, float ay1, float ax2, float ay2,
                                            float aarea, const float* __restrict__ g) {
  float gx1 = __fmul_rn(g[0], 0.0625f), gy1 = __fmul_rn(g[1], 0.0625f);
  float gx2 = __fmul_rn(g[2], 0.0625f), gy2 = __fmul_rn(g[3], 0.0625f);
  float ix1 = fmaxf(ax1, gx1), iy1 = fmaxf(ay1, gy1);
  float ix2 = fminf(ax2, gx2), iy2 = fminf(ay2, gy2);
  float inter = __fmul_rn(fmaxf(__fsub_rn(ix2, ix1), 0.f),
                          fmaxf(__fsub_rn(iy2, iy1), 0.f));
  float garea = __fmul_rn(__fsub_rn(gx2, gx1), __fsub_rn(gy2, gy1));
  float denom = __fadd_rn(__fsub_rn(__fadd_rn(aarea, garea), inter), 1e-8f);
  return __fdiv_rn(inter, denom);
}

// ---------- 1. features NCHW fp32 -> padded-record NHWC bf16 (LDS transpose) ----------
// grid (41, 2, 16): x = pos-tile (40 = border-zero tile), y = ci half, z = image.
// Read: float4 along pos (coalesced). Write: 64 contiguous B per thread.
__global__ __launch_bounds__(256) void k_featT(const float* __restrict__ feat,
                                               char* __restrict__ featT2) {
  const int tile = blockIdx.x;
  const int h    = blockIdx.y;
  const int b    = blockIdx.z;
  const int tid  = threadIdx.x;
  if (tile == 40) {                       // border: zero data bytes of 204 positions
    uint4 z = {0, 0, 0, 0};
    for (int u = tid; u < 204 * 8; u += 256) {
      int p = u >> 3, rec = u & 7;
      int ip, jp;
      if (p < 52)       { ip = 0;       jp = p; }
      else if (p < 104) { ip = 51;      jp = p - 52; }
      else if (p < 154) { ip = p - 103; jp = 0; }
      else              { ip = p - 153; jp = 51; }
      char* dst = featT2 + (size_t)((b * 52 + ip) * 52 + jp) * FT_POS_B
                + (h * 8 + rec) * 80;
      *(uint4*)(dst)      = z;
      *(uint4*)(dst + 16) = z;
      *(uint4*)(dst + 32) = z;
      *(uint4*)(dst + 48) = z;
    }
    return;
  }
  __shared__ __align__(16) unsigned short sT[64][264];  // row 528 B (16B mult)
  const int pos0 = tile * 64;
  const float* fb = feat + (size_t)b * 1280000 + (size_t)h * 256 * 2500;
  const int psub = (tid & 15) * 4;
#pragma unroll 4
  for (int it = 0; it < 16; ++it) {
    int ci = it * 16 + (tid >> 4);
    int p = pos0 + psub;
    float4 v;
    if (p + 3 < 2500) {
      v = *(const float4*)(fb + (size_t)ci * 2500 + p);
    } else {
      v.x = fb[(size_t)ci * 2500 + min(p + 0, 2499)];
      v.y = fb[(size_t)ci * 2500 + min(p + 1, 2499)];
      v.z = fb[(size_t)ci * 2500 + min(p + 2, 2499)];
      v.w = fb[(size_t)ci * 2500 + min(p + 3, 2499)];
    }
    sT[psub + 0][ci] = f2bf(v.x);
    sT[psub + 1][ci] = f2bf(v.y);
    sT[psub + 2][ci] = f2bf(v.z);
    sT[psub + 3][ci] = f2bf(v.w);
  }
  __syncthreads();
#pragma unroll
  for (int q = 0; q < 2; ++q) {
    int u = tid + q * 256;
    int p = u >> 3, rec = u & 7;
    int gp = pos0 + p;
    if (gp >= 2500) continue;
    int i = gp / 50, j = gp - i * 50;
    char* dst = featT2 + (size_t)((b * 52 + i + 1) * 52 + (j + 1)) * FT_POS_B
              + (h * 8 + rec) * 80;
    const uint4* src = (const uint4*)&sT[p][rec * 32];
    uint4 a0 = src[0], a1 = src[1], a2 = src[2], a3 = src[3];
    *(uint4*)(dst)      = a0;
    *(uint4*)(dst + 16) = a1;
    *(uint4*)(dst + 32) = a2;
    *(uint4*)(dst + 48) = a3;
  }
}

// ---------- 2a. compose partials: part[cz][co][kmem], kmem = ci*9+tap ----------
__global__ __launch_bounds__(128) void k_weff1(const float* __restrict__ w1,
                                               const float* __restrict__ wc,
                                               const float* __restrict__ wb,
                                               float* __restrict__ part) {
  __shared__ float sW[48][64];
  const int t = threadIdx.x;
  const int kmem = blockIdx.x * 128 + t;
  const int cz = blockIdx.y;
#pragma unroll
  for (int q = 0; q < 24; ++q) {
    int idx = t + q * 128;
    int co = idx >> 6, cl = idx & 63;
    int c = cz * 64 + cl;
    float v = 0.f;
    if (co < 9) v = wc[co * 512 + c];
    else if (co < 45) v = wb[(co - 9) * 512 + c];
    sW[co][cl] = v;
  }
  __syncthreads();
  float acc[48];
#pragma unroll
  for (int co = 0; co < 48; ++co) acc[co] = 0.f;
  const float* w1p = w1 + (size_t)(cz * 64) * 4608 + kmem;
  for (int c4 = 0; c4 < 64; c4 += 4) {
    float f0 = w1p[(size_t)(c4 + 0) * 4608];
    float f1 = w1p[(size_t)(c4 + 1) * 4608];
    float f2 = w1p[(size_t)(c4 + 2) * 4608];
    float f3 = w1p[(size_t)(c4 + 3) * 4608];
#pragma unroll
    for (int co = 0; co < 48; ++co) {
      float4 wv = *(const float4*)&sW[co][c4];
      acc[co] += wv.x * f0 + wv.y * f1 + wv.z * f2 + wv.w * f3;
    }
  }
  float* dst = part + (size_t)cz * 221184 + kmem;
#pragma unroll
  for (int co = 0; co < 48; ++co) dst[(size_t)co * 4608] = acc[co];
}

// ---------- 2b. reduce partials -> W2 padded records (bf16) ----------
__global__ __launch_bounds__(256) void k_weff2(const float* __restrict__ part,
                                               unsigned short* __restrict__ w2) {
  int idx = blockIdx.x * 256 + threadIdx.x;   // < 276480 = 16*9*48*40
  int c = idx / 17280;  int r = idx - c * 17280;
  int tap = r / 1920;   int r2 = r - tap * 1920;
  int co = r2 / 40;     int e = r2 - co * 40;
  float s = 0.f;
  if (e < 32) {
    int ci = c * 32 + e;
    const float* p = part + (size_t)co * 4608 + ci * 9 + tap;
#pragma unroll
    for (int cz = 0; cz < 8; ++cz) s += p[(size_t)cz * 221184];
  }
  w2[idx] = f2bf(s);
}

// ---------- 2c. bias_eff[co] = b_head[co] + whead[co]·b1 ----------
__global__ __launch_bounds__(64) void k_bias(const float* __restrict__ wc,
                                             const float* __restrict__ wb,
                                             const float* __restrict__ b1,
                                             const float* __restrict__ bc,
                                             const float* __restrict__ bbx,
                                             float* __restrict__ bias_eff) {
  int co = blockIdx.x, l = threadIdx.x;
  float s = 0.f;
#pragma unroll
  for (int q = 0; q < 8; ++q) {
    int c = q * 64 + l;
    float wv = co < 9 ? wc[co * 512 + c] : (co < 45 ? wb[(co - 9) * 512 + c] : 0.f);
    s += wv * b1[c];
  }
  for (int o = 32; o; o >>= 1) s += __shfl_down(s, o, 64);
  if (l == 0)
    bias_eff[co] = s + (co < 9 ? bc[co] : (co < 45 ? bbx[co - 9] : 0.f));
}

// ---------- 3. per-(b,gt) max IoU (k_loss recomputes IoU bitwise-identically) ----------
__global__ __launch_bounds__(256) void k_iou(const float* __restrict__ gt_boxes,
                                             unsigned* __restrict__ mx) {
  int b = blockIdx.y;
  int n = blockIdx.x * 256 + threadIdx.x;
  float lm[16];
#pragma unroll
  for (int m = 0; m < 16; ++m) lm[m] = 0.f;
  if (n < 22500) {
    float ax1, ay1, ax2, ay2;
    anchor_strict(n, ax1, ay1, ax2, ay2);
    float aarea = __fmul_rn(__fsub_rn(ax2, ax1), __fsub_rn(ay2, ay1));
#pragma unroll
    for (int m = 0; m < 16; ++m)
      lm[m] = iou_strict(ax1, ay1, ax2, ay2, aarea, gt_boxes + (b * 16 + m) * 4);
  }
  __shared__ float red[4][16];
#pragma unroll
  for (int m = 0; m < 16; ++m) {
    float v = lm[m];
    for (int o = 32; o; o >>= 1) v = fmaxf(v, __shfl_down(v, o, 64));
    if ((threadIdx.x & 63) == 0) red[threadIdx.x >> 6][m] = v;
  }
  __syncthreads();
  if (threadIdx.x < 16) {
    float v = fmaxf(fmaxf(red[0][threadIdx.x], red[1][threadIdx.x]),
                    fmaxf(red[2][threadIdx.x], red[3][threadIdx.x]));
    atomicMax(mx + b * 16 + threadIdx.x, __float_as_uint(v));
  }
}

// ---------- 4. direct conv+head: spatial tiles, all 9 taps from LDS ----------
__global__ __launch_bounds__(256) void k_conv(const char* __restrict__ featT2,
                                              const char* __restrict__ w2,
                                              const float* __restrict__ beff,
                                              float* __restrict__ oh) {
  __shared__ __align__(16) char sF[2][19456];   // 225*80=18000 used; 18*1024 staged
  __shared__ __align__(16) char sA[2][34816];   // 9*48*80=34560; 34*1024 staged
  const int tid = threadIdx.x, lane = tid & 63, w = tid >> 6;
  const int bx = blockIdx.x;
  const int b = bx >> 4, tl = bx & 15, tr = tl >> 2, tc = tl & 3;
  const int i0 = tr * 13 - (tr == 3 ? 1 : 0);   // {0,13,26,38}
  const int TI = (tr >= 2) ? 12 : 13;
  const int j0 = tc * 13 - (tc == 3 ? 1 : 0);
  const int TJ = (tc >= 2) ? 12 : 13;
  const int TJ2 = TJ + 2;
  const int mcount = TI * TJ;
  const int pieces = (TI + 2) * TJ2 * 5;        // 16B pieces per chunk

  const char* srcF[5];
#pragma unroll
  for (int k = 0; k < 5; ++k) {
    int s = w * 5 + k;
    int pi = s * 64 + lane;
    if (pi >= pieces) pi = pieces - 1;
    int pos = pi / 5, pc = pi - pos * 5;
    int hi = pos / TJ2, hj = pos - hi * TJ2;
    srcF[k] = featT2 + (size_t)((b * 52 + i0 + hi) * 52 + (j0 + hj)) * FT_POS_B + pc * 16;
  }
  int idxB[3];
#pragma unroll
  for (int bf = 0; bf < 3; ++bf) {
    int p = (w * 3 + bf) * 16 + (lane & 15);
    if (p >= mcount) p = mcount - 1;
    int di = p / TJ, dj = p - di * TJ;
    idxB[bf] = (di * TJ2 + dj) * 80 + (lane >> 4) * 16;
  }
  const int aoff = (lane & 15) * 80 + (lane >> 4) * 16;
  int toff[9];
#pragma unroll
  for (int tp = 0; tp < 9; ++tp) toff[tp] = ((tp / 3) * TJ2 + (tp % 3)) * 80;

  f32x4 acc[3][3] = {};

  auto stage = [&](int c, int pb) {
#pragma unroll
    for (int k = 0; k < 5; ++k) {
      int s = w * 5 + k;
      if (s < 18) gl_lds16(srcF[k] + (size_t)c * 80, sF[pb] + s * 1024);
    }
#pragma unroll
    for (int k = 0; k < 9; ++k) {
      int s = w + 4 * k;
      if (s < 34)
        gl_lds16(w2 + (size_t)c * W2_CHUNK_B + s * 1024 + lane * 16, sA[pb] + s * 1024);
    }
  };

  stage(0, 0);
  __builtin_amdgcn_s_waitcnt(0);
  __syncthreads();

  for (int c = 0; c < 16; ++c) {
    int pb = c & 1;
    if (c < 15) stage(c + 1, pb ^ 1);
    const char* fA = sA[pb];
    const char* fB = sF[pb];
#pragma unroll
    for (int tp = 0; tp < 9; ++tp) {
      bf16x8 av[3], bv[3];
#pragma unroll
      for (int cf = 0; cf < 3; ++cf)
        av[cf] = *(const bf16x8*)(fA + tp * 3840 + cf * 1280 + aoff);
#pragma unroll
      for (int bf = 0; bf < 3; ++bf)
        bv[bf] = *(const bf16x8*)(fB + idxB[bf] + toff[tp]);
#pragma unroll
      for (int cf = 0; cf < 3; ++cf)
#pragma unroll
        for (int bf = 0; bf < 3; ++bf)
          acc[cf][bf] = __builtin_amdgcn_mfma_f32_16x16x32_bf16(av[cf], bv[bf], acc[cf][bf], 0, 0, 0);
    }
    __builtin_amdgcn_s_waitcnt(0);
    __syncthreads();
  }

  f32x4 bias[3];
#pragma unroll
  for (int cf = 0; cf < 3; ++cf)
    bias[cf] = *(const f32x4*)(beff + cf * 16 + (lane >> 4) * 4);
#pragma unroll
  for (int bf = 0; bf < 3; ++bf) {
    int p = (w * 3 + bf) * 16 + (lane & 15);
    if (p >= mcount) continue;
    int di = p / TJ, dj = p - di * TJ;
    int gm = (b * 50 + i0 + di) * 50 + (j0 + dj);
#pragma unroll
    for (int cf = 0; cf < 3; ++cf) {
      f32x4 v = acc[cf][bf];
#pragma unroll
      for (int r = 0; r < 4; ++r) v[r] += bias[cf][r];
      *(f32x4*)(oh + (size_t)gm * 48 + cf * 16 + (lane >> 4) * 4) = v;
    }
  }
}

// ---------- 5. loss pass: recompute IoU (strict), loss sums, proposals ----------
__global__ __launch_bounds__(256) void k_loss(const float* __restrict__ gt_boxes,
                                              const unsigned* __restrict__ mxbuf,
                                              const float* __restrict__ oh,
                                              float* __restrict__ accum,
                                              float* __restrict__ dout) {
  int b = blockIdx.y;
  int n = blockIdx.x * 256 + threadIdx.x;
  float s_np = 0.f, s_reg = 0.f, s_pos = 0.f, s_nc = 0.f, s_nl = 0.f;
  if (n < 22500) {
    float ax1, ay1, ax2, ay2;
    anchor_strict(n, ax1, ay1, ax2, ay2);
    float aarea = __fmul_rn(__fsub_rn(ax2, ax1), __fsub_rn(ay2, ay1));
    float acx = (ax1 + ax2) * 0.5f, acy = (ay1 + ay2) * 0.5f;
    float aw = fmaxf(ax2 - ax1, 1e-6f), ah = fmaxf(ay2 - ay1, 1e-6f);
    int ii = n / 450, rem = n - ii * 450, jj = rem / 9, a = rem - jj * 9;
    const float* row = oh + ((size_t)(b * 2500 + ii * 50 + jj)) * 48;
    float logit = row[a];
    float p0 = row[9 + a * 4], p1 = row[10 + a * 4];
    float p2 = row[11 + a * 4], p3 = row[12 + a * 4];
    int npos = 0;
    bool allneg = true;
#pragma unroll
    for (int m = 0; m < 16; ++m) {
      const float* g = gt_boxes + (b * 16 + m) * 4;
      float iou = iou_strict(ax1, ay1, ax2, ay2, aarea, g);
      float mxv = __uint_as_float(mxbuf[b * 16 + m]);
      bool pos = ((iou == mxv) && (mxv > 0.f)) || (iou > 0.7f);
      if (iou >= 0.3f) allneg = false;
      if (pos) {
        ++npos;
        float gx1 = g[0] * 0.0625f, gy1 = g[1] * 0.0625f;
        float gx2 = g[2] * 0.0625f, gy2 = g[3] * 0.0625f;
        float gcx = (gx1 + gx2) * 0.5f, gcy = (gy1 + gy2) * 0.5f;
        float gw = fmaxf(gx2 - gx1, 1e-6f), gh = fmaxf(gy2 - gy1, 1e-6f);
        float tx = (gcx - acx) / aw, ty = (gcy - acy) / ah;
        float twv = logf(gw / aw), thv = logf(gh / ah);
        s_reg += sl1(tx - p0) + sl1(ty - p1) + sl1(twv - p2) + sl1(thv - p3);
      }
    }
    s_np = (float)npos;
    s_pos = (float)npos * softplus_f(-logit);
    if (allneg) { s_nc = 1.f; s_nl = softplus_f(logit); }
    float pcx = acx + p0 * aw, pcy = acy + p1 * ah;
    float pw = aw * expf(p2), ph = ah * expf(p3);
    float* o = dout + 1 + ((size_t)b * 22500 + n) * 4;
    o[0] = pcx - pw * 0.5f;
    o[1] = pcy - ph * 0.5f;
    o[2] = pcx + pw * 0.5f;
    o[3] = pcy + ph * 0.5f;
  }
  float vals[5] = {s_np, s_reg, s_pos, s_nc, s_nl};
  __shared__ float red[4][5];
#pragma unroll
  for (int q = 0; q < 5; ++q) {
    float v = vals[q];
    for (int o = 32; o; o >>= 1) v += __shfl_down(v, o, 64);
    if ((threadIdx.x & 63) == 0) red[threadIdx.x >> 6][q] = v;
  }
  __syncthreads();
  if (threadIdx.x < 5) {
    float v = red[0][threadIdx.x] + red[1][threadIdx.x] +
              red[2][threadIdx.x] + red[3][threadIdx.x];
    atomicAdd(accum + threadIdx.x, v);
  }
}

// ---------- 6. finalize ----------
__global__ void k_fin(const float* __restrict__ accum, float* __restrict__ dout) {
  if (threadIdx.x == 0 && blockIdx.x == 0) {
    float np = fmaxf(accum[0], 1.f);
    float nn = fmaxf(accum[3], 1.f);
    float loss = 0.5f * (accum[2] / np + accum[4] / nn) + 5.f * (accum[1] / (4.f * np));
    dout[0] = loss;
  }
}

// ---------- launch ----------
extern "C" void kernel_launch(void* const* d_in, const int* in_sizes, int n_in,
                              void* d_out, int out_size, void* d_ws, size_t ws_size,
                              hipStream_t stream) {
  const float* features = (const float*)d_in[0];
  const float* gt_boxes = (const float*)d_in[1];
  const float* w1    = (const float*)d_in[2];
  const float* b1    = (const float*)d_in[3];
  const float* w_cls = (const float*)d_in[4];
  const float* b_cls = (const float*)d_in[5];
  const float* w_box = (const float*)d_in[6];
  const float* b_box = (const float*)d_in[7];
  float* out = (float*)d_out;
  char* ws = (char*)d_ws;

  // ws layout
  char*           featT2 = ws;                                  // 55,377,920 B
  unsigned short* w2     = (unsigned short*)(ws + 55377920);    //    552,960 B
  float*          wpart  = (float*)(ws + 55930880);             //  7,077,888 B
  float*          oh     = (float*)(ws + 63008768);             //  7,680,000 B
  float*          beff   = (float*)(ws + 70688768);             //        192 B
  unsigned*       mx     = (unsigned*)(ws + 70688960);          //      1,024 B
  float*          accum  = (float*)(ws + 70689984);             //         32 B

  hipMemsetAsync(ws + 70688960, 0, 1056, stream);               // maxiou + accums

  k_featT<<<dim3(41, 2, 16), 256, 0, stream>>>(features, featT2);
  k_weff1<<<dim3(36, 8), 128, 0, stream>>>(w1, w_cls, w_box, wpart);
  k_weff2<<<1080, 256, 0, stream>>>(wpart, w2);
  k_bias<<<48, 64, 0, stream>>>(w_cls, w_box, b1, b_cls, b_box, beff);
  k_iou<<<dim3(88, 16), 256, 0, stream>>>(gt_boxes, mx);
  k_conv<<<256, 256, 0, stream>>>(featT2, (const char*)w2, beff, oh);
  k_loss<<<dim3(88, 16), 256, 0, stream>>>(gt_boxes, mx, oh, accum, out);
  k_fin<<<1, 64, 0, stream>>>(accum, out);
}

// Round 7
// 276.115 us; speedup vs baseline: 2.2195x; 1.0139x over previous
//
#include <hip/hip_runtime.h>
#include <hip/hip_bf16.h>
#include <stdint.h>

using bf16x8 = __attribute__((ext_vector_type(8))) __bf16;
using f32x4  = __attribute__((ext_vector_type(4))) float;

// featT2 layout: [16][52][52] positions (row/col 0,51 = zero borders), each
// position = 16 ci-chunks x 64 B PACKED (32 bf16). All data bytes written every
// call by k_featT (interior tiles + border tile); no memset, no write holes.
// k_conv's LDS keeps 80 B records (20-bank stride, conflict-free fragments);
// the 16 B LDS pad piece is staged as a duplicate of piece 3 and never read.
#define FT_POS_B 1024
// W2 layout: [ci-chunk 16][tap 9][co 48][80 B record] (small, stays padded)
#define W2_CHUNK_B 34560

// ---------- helpers ----------
__device__ __forceinline__ unsigned short f2bf(float f) {
  union { float f; unsigned u; } x; x.f = f;
  unsigned r = x.u + 0x7fffu + ((x.u >> 16) & 1u);   // RNE
  return (unsigned short)(r >> 16);
}

__device__ __forceinline__ void gl_lds16(const void* g, void* l) {
  __builtin_amdgcn_global_load_lds(
      (const __attribute__((address_space(1))) void*)g,
      (__attribute__((address_space(3))) void*)l, 16, 0, 0);
}

__device__ __forceinline__ float sl1(float d) {
  float ad = fabsf(d);
  return ad < 1.f ? 0.5f * d * d : ad - 0.5f;
}
__device__ __forceinline__ float softplus_f(float x) {
  return fmaxf(x, 0.f) + log1pf(expf(-fabsf(x)));
}

// strict-fp anchor + IoU: identical bits in k_iou and k_loss (no contraction
// possible through __f*_rn intrinsics) so the (iou == max) test is exact.
__device__ __forceinline__ void anchor_strict(int n, float& ax1, float& ay1,
                                              float& ax2, float& ay2) {
  int ii = n / 450;
  int rem = n - ii * 450;
  int jj = rem / 9;
  int a  = rem - jj * 9;
  const float SC[3] = {2.f, 4.f, 6.f};
  const float RA[3] = {0.5f, 1.f, 1.5f};
  float w = __fmul_rn(SC[a % 3], RA[a / 3]);
  float h = SC[a % 3];
  float cx = __fadd_rn((float)ii, 0.5f);
  float cy = __fadd_rn((float)jj, 0.5f);
  float wh = __fmul_rn(w, 0.5f), hh = __fmul_rn(h, 0.5f);
  ax1 = fminf(fmaxf(__fsub_rn(cx, wh), 0.f), 50.f);
  ax2 = fminf(fmaxf(__fadd_rn(cx, wh), 0.f), 50.f);
  ay1 = fminf(fmaxf(__fsub_rn(cy, hh), 0.f), 50.f);
  ay2 = fminf(fmaxf(__fadd_rn(cy, hh), 0.f), 50.f);
}
__device__ __forceinline__ float iou_strict(float ax1, float ay1, float ax2, float ay2,
                                            float aarea, const float* __restrict__ g) {
  float gx1 = __fmul_rn(g[0], 0.0625f), gy1 = __fmul_rn(g[1], 0.0625f);
  float gx2 = __fmul_rn(g[2], 0.0625f), gy2 = __fmul_rn(g[3], 0.0625f);
  float ix1 = fmaxf(ax1, gx1), iy1 = fmaxf(ay1, gy1);
  float ix2 = fminf(ax2, gx2), iy2 = fminf(ay2, gy2);
  float inter = __fmul_rn(fmaxf(__fsub_rn(ix2, ix1), 0.f),
                          fmaxf(__fsub_rn(iy2, iy1), 0.f));
  float garea = __fmul_rn(__fsub_rn(gx2, gx1), __fsub_rn(gy2, gy1));
  float denom = __fadd_rn(__fsub_rn(__fadd_rn(aarea, garea), inter), 1e-8f);
  return __fdiv_rn(inter, denom);
}

// ---------- 1. features NCHW fp32 -> packed-record NHWC bf16 (LDS transpose) ----------
// grid (80, 2, 16): x = 32-pos tile (79 = border-zero tile), y = ci half, z = image.
// Read: float4 along pos (coalesced, 128 B/ci-row/wave). Write: 64 contiguous B
// per thread, 512 B-aligned dense blocks -> no partial cache lines.
__global__ __launch_bounds__(256) void k_featT(const float* __restrict__ feat,
                                               char* __restrict__ featT2) {
  const int tile = blockIdx.x;
  const int h    = blockIdx.y;
  const int b    = blockIdx.z;
  const int tid  = threadIdx.x;
  if (tile == 79) {                       // border: zero 204 positions' data
    uint4 z = {0, 0, 0, 0};
    for (int u = tid; u < 204 * 8; u += 256) {
      int p = u >> 3, rec = u & 7;
      int ip, jp;
      if (p < 52)       { ip = 0;       jp = p; }
      else if (p < 104) { ip = 51;      jp = p - 52; }
      else if (p < 154) { ip = p - 103; jp = 0; }
      else              { ip = p - 153; jp = 51; }
      char* dst = featT2 + (size_t)((b * 52 + ip) * 52 + jp) * FT_POS_B
                + (h * 8 + rec) * 64;
      *(uint4*)(dst)      = z;
      *(uint4*)(dst + 16) = z;
      *(uint4*)(dst + 32) = z;
      *(uint4*)(dst + 48) = z;
    }
    return;
  }
  __shared__ __align__(16) unsigned short sT[32][264];  // row 528 B
  const int pos0 = tile * 32;
  const float* fb = feat + (size_t)b * 1280000 + (size_t)h * 256 * 2500;
  const int psub = (tid & 7) * 4;
  const int cio  = tid >> 3;              // 0..31
#pragma unroll
  for (int it = 0; it < 8; ++it) {
    int ci = it * 32 + cio;
    int p = pos0 + psub;
    float4 v;
    if (p + 3 < 2500) {
      v = *(const float4*)(fb + (size_t)ci * 2500 + p);
    } else {
      v.x = fb[(size_t)ci * 2500 + min(p + 0, 2499)];
      v.y = fb[(size_t)ci * 2500 + min(p + 1, 2499)];
      v.z = fb[(size_t)ci * 2500 + min(p + 2, 2499)];
      v.w = fb[(size_t)ci * 2500 + min(p + 3, 2499)];
    }
    sT[psub + 0][ci] = f2bf(v.x);
    sT[psub + 1][ci] = f2bf(v.y);
    sT[psub + 2][ci] = f2bf(v.z);
    sT[psub + 3][ci] = f2bf(v.w);
  }
  __syncthreads();
  {
    int p = tid >> 3, rec = tid & 7;
    int gp = pos0 + p;
    if (gp < 2500) {
      int i = gp / 50, j = gp - i * 50;
      char* dst = featT2 + (size_t)((b * 52 + i + 1) * 52 + (j + 1)) * FT_POS_B
                + (h * 8 + rec) * 64;
      const uint4* src = (const uint4*)&sT[p][rec * 32];
      uint4 a0 = src[0], a1 = src[1], a2 = src[2], a3 = src[3];
      *(uint4*)(dst)      = a0;
      *(uint4*)(dst + 16) = a1;
      *(uint4*)(dst + 32) = a2;
      *(uint4*)(dst + 48) = a3;
    }
  }
}

// ---------- 2a. compose partials: part[cz][co][kmem], kmem = ci*9+tap ----------
__global__ __launch_bounds__(128) void k_weff1(const float* __restrict__ w1,
                                               const float* __restrict__ wc,
                                               const float* __restrict__ wb,
                                               float* __restrict__ part) {
  __shared__ float sW[48][64];
  const int t = threadIdx.x;
  const int kmem = blockIdx.x * 128 + t;
  const int cz = blockIdx.y;
#pragma unroll
  for (int q = 0; q < 24; ++q) {
    int idx = t + q * 128;
    int co = idx >> 6, cl = idx & 63;
    int c = cz * 64 + cl;
    float v = 0.f;
    if (co < 9) v = wc[co * 512 + c];
    else if (co < 45) v = wb[(co - 9) * 512 + c];
    sW[co][cl] = v;
  }
  __syncthreads();
  float acc[48];
#pragma unroll
  for (int co = 0; co < 48; ++co) acc[co] = 0.f;
  const float* w1p = w1 + (size_t)(cz * 64) * 4608 + kmem;
  for (int c4 = 0; c4 < 64; c4 += 4) {
    float f0 = w1p[(size_t)(c4 + 0) * 4608];
    float f1 = w1p[(size_t)(c4 + 1) * 4608];
    float f2 = w1p[(size_t)(c4 + 2) * 4608];
    float f3 = w1p[(size_t)(c4 + 3) * 4608];
#pragma unroll
    for (int co = 0; co < 48; ++co) {
      float4 wv = *(const float4*)&sW[co][c4];
      acc[co] += wv.x * f0 + wv.y * f1 + wv.z * f2 + wv.w * f3;
    }
  }
  float* dst = part + (size_t)cz * 221184 + kmem;
#pragma unroll
  for (int co = 0; co < 48; ++co) dst[(size_t)co * 4608] = acc[co];
}

// ---------- 2b. reduce partials -> W2 padded records (bf16) ----------
__global__ __launch_bounds__(256) void k_weff2(const float* __restrict__ part,
                                               unsigned short* __restrict__ w2) {
  int idx = blockIdx.x * 256 + threadIdx.x;   // < 276480 = 16*9*48*40
  int c = idx / 17280;  int r = idx - c * 17280;
  int tap = r / 1920;   int r2 = r - tap * 1920;
  int co = r2 / 40;     int e = r2 - co * 40;
  float s = 0.f;
  if (e < 32) {
    int ci = c * 32 + e;
    const float* p = part + (size_t)co * 4608 + ci * 9 + tap;
#pragma unroll
    for (int cz = 0; cz < 8; ++cz) s += p[(size_t)cz * 221184];
  }
  w2[idx] = f2bf(s);
}

// ---------- 2c. bias_eff[co] = b_head[co] + whead[co]·b1 ----------
__global__ __launch_bounds__(64) void k_bias(const float* __restrict__ wc,
                                             const float* __restrict__ wb,
                                             const float* __restrict__ b1,
                                             const float* __restrict__ bc,
                                             const float* __restrict__ bbx,
                                             float* __restrict__ bias_eff) {
  int co = blockIdx.x, l = threadIdx.x;
  float s = 0.f;
#pragma unroll
  for (int q = 0; q < 8; ++q) {
    int c = q * 64 + l;
    float wv = co < 9 ? wc[co * 512 + c] : (co < 45 ? wb[(co - 9) * 512 + c] : 0.f);
    s += wv * b1[c];
  }
  for (int o = 32; o; o >>= 1) s += __shfl_down(s, o, 64);
  if (l == 0)
    bias_eff[co] = s + (co < 9 ? bc[co] : (co < 45 ? bbx[co - 9] : 0.f));
}

// ---------- 3. per-(b,gt) max IoU (k_loss recomputes IoU bitwise-identically) ----------
__global__ __launch_bounds__(256) void k_iou(const float* __restrict__ gt_boxes,
                                             unsigned* __restrict__ mx) {
  int b = blockIdx.y;
  int n = blockIdx.x * 256 + threadIdx.x;
  float lm[16];
#pragma unroll
  for (int m = 0; m < 16; ++m) lm[m] = 0.f;
  if (n < 22500) {
    float ax1, ay1, ax2, ay2;
    anchor_strict(n, ax1, ay1, ax2, ay2);
    float aarea = __fmul_rn(__fsub_rn(ax2, ax1), __fsub_rn(ay2, ay1));
#pragma unroll
    for (int m = 0; m < 16; ++m)
      lm[m] = iou_strict(ax1, ay1, ax2, ay2, aarea, gt_boxes + (b * 16 + m) * 4);
  }
  __shared__ float red[4][16];
#pragma unroll
  for (int m = 0; m < 16; ++m) {
    float v = lm[m];
    for (int o = 32; o; o >>= 1) v = fmaxf(v, __shfl_down(v, o, 64));
    if ((threadIdx.x & 63) == 0) red[threadIdx.x >> 6][m] = v;
  }
  __syncthreads();
  if (threadIdx.x < 16) {
    float v = fmaxf(fmaxf(red[0][threadIdx.x], red[1][threadIdx.x]),
                    fmaxf(red[2][threadIdx.x], red[3][threadIdx.x]));
    atomicMax(mx + b * 16 + threadIdx.x, __float_as_uint(v));
  }
}

// ---------- 4. direct conv+head: spatial tiles, all 9 taps from LDS ----------
__global__ __launch_bounds__(256) void k_conv(const char* __restrict__ featT2,
                                              const char* __restrict__ w2,
                                              const float* __restrict__ beff,
                                              float* __restrict__ oh) {
  __shared__ __align__(16) char sF[2][19456];   // 225*80=18000 used; 18*1024 staged
  __shared__ __align__(16) char sA[2][34816];   // 9*48*80=34560; 34*1024 staged
  const int tid = threadIdx.x, lane = tid & 63, w = tid >> 6;
  const int bx = blockIdx.x;
  const int b = bx >> 4, tl = bx & 15, tr = tl >> 2, tc = tl & 3;
  const int i0 = tr * 13 - (tr == 3 ? 1 : 0);   // {0,13,26,38}
  const int TI = (tr >= 2) ? 12 : 13;
  const int j0 = tc * 13 - (tc == 3 ? 1 : 0);
  const int TJ = (tc >= 2) ? 12 : 13;
  const int TJ2 = TJ + 2;
  const int mcount = TI * TJ;
  const int pieces = (TI + 2) * TJ2 * 5;        // LDS 16B pieces per chunk

  // sF staging: LDS piece pi -> (pos, pc); pc==4 is the LDS pad piece, staged
  // as a duplicate of global piece 3 (packed 64 B records) — never read.
  const char* srcF[5];
#pragma unroll
  for (int k = 0; k < 5; ++k) {
    int s = w * 5 + k;
    int pi = s * 64 + lane;
    if (pi >= pieces) pi = pieces - 1;
    int pos = pi / 5, pc = pi - pos * 5;
    if (pc > 3) pc = 3;
    int hi = pos / TJ2, hj = pos - hi * TJ2;
    srcF[k] = featT2 + (size_t)((b * 52 + i0 + hi) * 52 + (j0 + hj)) * FT_POS_B + pc * 16;
  }
  int idxB[3];
#pragma unroll
  for (int bf = 0; bf < 3; ++bf) {
    int p = (w * 3 + bf) * 16 + (lane & 15);
    if (p >= mcount) p = mcount - 1;
    int di = p / TJ, dj = p - di * TJ;
    idxB[bf] = (di * TJ2 + dj) * 80 + (lane >> 4) * 16;
  }
  const int aoff = (lane & 15) * 80 + (lane >> 4) * 16;
  int toff[9];
#pragma unroll
  for (int tp = 0; tp < 9; ++tp) toff[tp] = ((tp / 3) * TJ2 + (tp % 3)) * 80;

  f32x4 acc[3][3] = {};

  auto stage = [&](int c, int pb) {
#pragma unroll
    for (int k = 0; k < 5; ++k) {
      int s = w * 5 + k;
      if (s < 18) gl_lds16(srcF[k] + (size_t)c * 64, sF[pb] + s * 1024);
    }
#pragma unroll
    for (int k = 0; k < 9; ++k) {
      int s = w + 4 * k;
      if (s < 34)
        gl_lds16(w2 + (size_t)c * W2_CHUNK_B + s * 1024 + lane * 16, sA[pb] + s * 1024);
    }
  };

  stage(0, 0);
  __builtin_amdgcn_s_waitcnt(0);
  __syncthreads();

  for (int c = 0; c < 16; ++c) {
    int pb = c & 1;
    if (c < 15) stage(c + 1, pb ^ 1);
    const char* fA = sA[pb];
    const char* fB = sF[pb];
#pragma unroll
    for (int tp = 0; tp < 9; ++tp) {
      bf16x8 av[3], bv[3];
#pragma unroll
      for (int cf = 0; cf < 3; ++cf)
        av[cf] = *(const bf16x8*)(fA + tp * 3840 + cf * 1280 + aoff);
#pragma unroll
      for (int bf = 0; bf < 3; ++bf)
        bv[bf] = *(const bf16x8*)(fB + idxB[bf] + toff[tp]);
#pragma unroll
      for (int cf = 0; cf < 3; ++cf)
#pragma unroll
        for (int bf = 0; bf < 3; ++bf)
          acc[cf][bf] = __builtin_amdgcn_mfma_f32_16x16x32_bf16(av[cf], bv[bf], acc[cf][bf], 0, 0, 0);
    }
    __builtin_amdgcn_s_waitcnt(0);
    __syncthreads();
  }

  f32x4 bias[3];
#pragma unroll
  for (int cf = 0; cf < 3; ++cf)
    bias[cf] = *(const f32x4*)(beff + cf * 16 + (lane >> 4) * 4);
#pragma unroll
  for (int bf = 0; bf < 3; ++bf) {
    int p = (w * 3 + bf) * 16 + (lane & 15);
    if (p >= mcount) continue;
    int di = p / TJ, dj = p - di * TJ;
    int gm = (b * 50 + i0 + di) * 50 + (j0 + dj);
#pragma unroll
    for (int cf = 0; cf < 3; ++cf) {
      f32x4 v = acc[cf][bf];
#pragma unroll
      for (int r = 0; r < 4; ++r) v[r] += bias[cf][r];
      *(f32x4*)(oh + (size_t)gm * 48 + cf * 16 + (lane >> 4) * 4) = v;
    }
  }
}

// ---------- 5. loss pass: recompute IoU (strict), loss sums, proposals ----------
__global__ __launch_bounds__(256) void k_loss(const float* __restrict__ gt_boxes,
                                              const unsigned* __restrict__ mxbuf,
                                              const float* __restrict__ oh,
                                              float* __restrict__ accum,
                                              float* __restrict__ dout) {
  int b = blockIdx.y;
  int n = blockIdx.x * 256 + threadIdx.x;
  float s_np = 0.f, s_reg = 0.f, s_pos = 0.f, s_nc = 0.f, s_nl = 0.f;
  if (n < 22500) {
    float ax1, ay1, ax2, ay2;
    anchor_strict(n, ax1, ay1, ax2, ay2);
    float aarea = __fmul_rn(__fsub_rn(ax2, ax1), __fsub_rn(ay2, ay1));
    float acx = (ax1 + ax2) * 0.5f, acy = (ay1 + ay2) * 0.5f;
    float aw = fmaxf(ax2 - ax1, 1e-6f), ah = fmaxf(ay2 - ay1, 1e-6f);
    int ii = n / 450, rem = n - ii * 450, jj = rem / 9, a = rem - jj * 9;
    const float* row = oh + ((size_t)(b * 2500 + ii * 50 + jj)) * 48;
    float logit = row[a];
    float p0 = row[9 + a * 4], p1 = row[10 + a * 4];
    float p2 = row[11 + a * 4], p3 = row[12 + a * 4];
    int npos = 0;
    bool allneg = true;
#pragma unroll
    for (int m = 0; m < 16; ++m) {
      const float* g = gt_boxes + (b * 16 + m) * 4;
      float iou = iou_strict(ax1, ay1, ax2, ay2, aarea, g);
      float mxv = __uint_as_float(mxbuf[b * 16 + m]);
      bool pos = ((iou == mxv) && (mxv > 0.f)) || (iou > 0.7f);
      if (iou >= 0.3f) allneg = false;
      if (pos) {
        ++npos;
        float gx1 = g[0] * 0.0625f, gy1 = g[1] * 0.0625f;
        float gx2 = g[2] * 0.0625f, gy2 = g[3] * 0.0625f;
        float gcx = (gx1 + gx2) * 0.5f, gcy = (gy1 + gy2) * 0.5f;
        float gw = fmaxf(gx2 - gx1, 1e-6f), gh = fmaxf(gy2 - gy1, 1e-6f);
        float tx = (gcx - acx) / aw, ty = (gcy - acy) / ah;
        float twv = logf(gw / aw), thv = logf(gh / ah);
        s_reg += sl1(tx - p0) + sl1(ty - p1) + sl1(twv - p2) + sl1(thv - p3);
      }
    }
    s_np = (float)npos;
    s_pos = (float)npos * softplus_f(-logit);
    if (allneg) { s_nc = 1.f; s_nl = softplus_f(logit); }
    float pcx = acx + p0 * aw, pcy = acy + p1 * ah;
    float pw = aw * expf(p2), ph = ah * expf(p3);
    float* o = dout + 1 + ((size_t)b * 22500 + n) * 4;
    o[0] = pcx - pw * 0.5f;
    o[1] = pcy - ph * 0.5f;
    o[2] = pcx + pw * 0.5f;
    o[3] = pcy + ph * 0.5f;
  }
  float vals[5] = {s_np, s_reg, s_pos, s_nc, s_nl};
  __shared__ float red[4][5];
#pragma unroll
  for (int q = 0; q < 5; ++q) {
    float v = vals[q];
    for (int o = 32; o; o >>= 1) v += __shfl_down(v, o, 64);
    if ((threadIdx.x & 63) == 0) red[threadIdx.x >> 6][q] = v;
  }
  __syncthreads();
  if (threadIdx.x < 5) {
    float v = red[0][threadIdx.x] + red[1][threadIdx.x] +
              red[2][threadIdx.x] + red[3][threadIdx.x];
    atomicAdd(accum + threadIdx.x, v);
  }
}

// ---------- 6. finalize ----------
__global__ void k_fin(const float* __restrict__ accum, float* __restrict__ dout) {
  if (threadIdx.x == 0 && blockIdx.x == 0) {
    float np = fmaxf(accum[0], 1.f);
    float nn = fmaxf(accum[3], 1.f);
    float loss = 0.5f * (accum[2] / np + accum[4] / nn) + 5.f * (accum[1] / (4.f * np));
    dout[0] = loss;
  }
}

// ---------- launch ----------
extern "C" void kernel_launch(void* const* d_in, const int* in_sizes, int n_in,
                              void* d_out, int out_size, void* d_ws, size_t ws_size,
                              hipStream_t stream) {
  const float* features = (const float*)d_in[0];
  const float* gt_boxes = (const float*)d_in[1];
  const float* w1    = (const float*)d_in[2];
  const float* b1    = (const float*)d_in[3];
  const float* w_cls = (const float*)d_in[4];
  const float* b_cls = (const float*)d_in[5];
  const float* w_box = (const float*)d_in[6];
  const float* b_box = (const float*)d_in[7];
  float* out = (float*)d_out;
  char* ws = (char*)d_ws;

  // ws layout (featT2 packed: 16*52*52*1024 = 44,302,336 B)
  char*           featT2 = ws;                                  // 44,302,336 B
  unsigned short* w2     = (unsigned short*)(ws + 44302336);    //    552,960 B
  float*          wpart  = (float*)(ws + 44855296);             //  7,077,888 B
  float*          oh     = (float*)(ws + 51933184);             //  7,680,000 B
  float*          beff   = (float*)(ws + 59613184);             //        192 B
  unsigned*       mx     = (unsigned*)(ws + 59613376);          //      1,024 B
  float*          accum  = (float*)(ws + 59614400);             //         32 B

  hipMemsetAsync(ws + 59613376, 0, 1056, stream);               // maxiou + accums

  k_featT<<<dim3(80, 2, 16), 256, 0, stream>>>(features, featT2);
  k_weff1<<<dim3(36, 8), 128, 0, stream>>>(w1, w_cls, w_box, wpart);
  k_weff2<<<1080, 256, 0, stream>>>(wpart, w2);
  k_bias<<<48, 64, 0, stream>>>(w_cls, w_box, b1, b_cls, b_box, beff);
  k_iou<<<dim3(88, 16), 256, 0, stream>>>(gt_boxes, mx);
  k_conv<<<256, 256, 0, stream>>>(featT2, (const char*)w2, beff, oh);
  k_loss<<<dim3(88, 16), 256, 0, stream>>>(gt_boxes, mx, oh, accum, out);
  k_fin<<<1, 64, 0, stream>>>(accum, out);
}

// Round 8
// 269.903 us; speedup vs baseline: 2.2705x; 1.0230x over previous
//
#include <hip/hip_runtime.h>
#include <hip/hip_bf16.h>
#include <stdint.h>

using bf16x8 = __attribute__((ext_vector_type(8))) __bf16;
using f32x4  = __attribute__((ext_vector_type(4))) float;

// featT2 layout: [16][52][52] positions (row/col 0,51 = zero borders), each
// position = 16 ci-chunks x 64 B PACKED (32 bf16). All data bytes written every
// call by k_featT (interior tiles + border tile); no memset.
// k_conv's LDS keeps 80 B records (20-bank stride, conflict-free fragments);
// the 16 B LDS pad piece is staged as a duplicate of piece 3 and never read.
#define FT_POS_B 1024
// W2 layout: [ci-chunk 16][tap 9][co 48][80 B record] (small, stays padded)
#define W2_CHUNK_B 34560

// ---------- helpers ----------
__device__ __forceinline__ unsigned short f2bf(float f) {
  union { float f; unsigned u; } x; x.f = f;
  unsigned r = x.u + 0x7fffu + ((x.u >> 16) & 1u);   // RNE
  return (unsigned short)(r >> 16);
}

__device__ __forceinline__ void gl_lds16(const void* g, void* l) {
  __builtin_amdgcn_global_load_lds(
      (const __attribute__((address_space(1))) void*)g,
      (__attribute__((address_space(3))) void*)l, 16, 0, 0);
}

__device__ __forceinline__ float sl1(float d) {
  float ad = fabsf(d);
  return ad < 1.f ? 0.5f * d * d : ad - 0.5f;
}
__device__ __forceinline__ float softplus_f(float x) {
  return fmaxf(x, 0.f) + log1pf(expf(-fabsf(x)));
}

// strict-fp anchor + IoU: identical bits in k_iou and k_loss (no contraction
// possible through __f*_rn intrinsics) so the (iou == max) test is exact.
__device__ __forceinline__ void anchor_strict(int n, float& ax1, float& ay1,
                                              float& ax2, float& ay2) {
  int ii = n / 450;
  int rem = n - ii * 450;
  int jj = rem / 9;
  int a  = rem - jj * 9;
  const float SC[3] = {2.f, 4.f, 6.f};
  const float RA[3] = {0.5f, 1.f, 1.5f};
  float w = __fmul_rn(SC[a % 3], RA[a / 3]);
  float h = SC[a % 3];
  float cx = __fadd_rn((float)ii, 0.5f);
  float cy = __fadd_rn((float)jj, 0.5f);
  float wh = __fmul_rn(w, 0.5f), hh = __fmul_rn(h, 0.5f);
  ax1 = fminf(fmaxf(__fsub_rn(cx, wh), 0.f), 50.f);
  ax2 = fminf(fmaxf(__fadd_rn(cx, wh), 0.f), 50.f);
  ay1 = fminf(fmaxf(__fsub_rn(cy, hh), 0.f), 50.f);
  ay2 = fminf(fmaxf(__fadd_rn(cy, hh), 0.f), 50.f);
}
__device__ __forceinline__ float iou_strict(float ax1, float ay1, float ax2, float ay2,
                                            float aarea, const float* __restrict__ g) {
  float gx1 = __fmul_rn(g[0], 0.0625f), gy1 = __fmul_rn(g[1], 0.0625f);
  float gx2 = __fmul_rn(g[2], 0.0625f), gy2 = __fmul_rn(g[3], 0.0625f);
  float ix1 = fmaxf(ax1, gx1), iy1 = fmaxf(ay1, gy1);
  float ix2 = fminf(ax2, gx2), iy2 = fminf(ay2, gy2);
  float inter = __fmul_rn(fmaxf(__fsub_rn(ix2, ix1), 0.f),
                          fmaxf(__fsub_rn(iy2, iy1), 0.f));
  float garea = __fmul_rn(__fsub_rn(gx2, gx1), __fsub_rn(gy2, gy1));
  float denom = __fadd_rn(__fsub_rn(__fadd_rn(aarea, garea), inter), 1e-8f);
  return __fdiv_rn(inter, denom);
}

// ---------- 1. features NCHW fp32 -> packed-record NHWC bf16 (LDS transpose) ----------
// grid (21, 4, 16): x = 128-pos tile (20 = border-zero), y = 128-ci group, z = image.
// Read: lanes along pos -> one wave-load = 2 ci-rows x 512 B CONTIGUOUS (R7 was
// 128 B/segment at 10 KB stride -> DRAM-page-bound at 2.4 TB/s).
// Transpose store: 4 consecutive ci packed per position -> ds_write_b64.
// Write: 64 B/thread LDS-row reads -> 256 B contiguous global segments.
__global__ __launch_bounds__(256) void k_featT(const float* __restrict__ feat,
                                               char* __restrict__ featT2) {
  const int tile = blockIdx.x;
  const int g    = blockIdx.y;            // ci group: chunks g*4..g*4+3
  const int b    = blockIdx.z;
  const int tid  = threadIdx.x;
  if (tile == 20) {                       // border: zero 204 positions' chunks
    uint4 z = {0, 0, 0, 0};
    for (int u = tid; u < 204 * 4; u += 256) {
      int p = u >> 2, c4 = u & 3;
      int ip, jp;
      if (p < 52)       { ip = 0;       jp = p; }
      else if (p < 104) { ip = 51;      jp = p - 52; }
      else if (p < 154) { ip = p - 103; jp = 0; }
      else              { ip = p - 153; jp = 51; }
      char* dst = featT2 + (size_t)((b * 52 + ip) * 52 + jp) * FT_POS_B
                + (g * 4 + c4) * 64;
      *(uint4*)(dst)      = z;
      *(uint4*)(dst + 16) = z;
      *(uint4*)(dst + 32) = z;
      *(uint4*)(dst + 48) = z;
    }
    return;
  }
  __shared__ __align__(16) unsigned short sT[128 * 132];  // row stride 264 B
  const int pos0 = tile * 128;
  const float* fb = feat + (size_t)b * 1280000 + (size_t)(g * 128) * 2500;
  const int pq = tid & 31;                // pos quad: pos0 + pq*4 .. +3
  const int rg = tid >> 5;                // ci row-group (4 rows), 0..7
  const int p  = pos0 + pq * 4;
#pragma unroll
  for (int it = 0; it < 4; ++it) {
    int cb = it * 32 + rg * 4;            // ci within group
    float vv[4][4];
#pragma unroll
    for (int q = 0; q < 4; ++q) {
      const float* src = fb + (size_t)(cb + q) * 2500 + p;
      if (p + 3 < 2500) {
        float4 v = *(const float4*)src;
        vv[q][0] = v.x; vv[q][1] = v.y; vv[q][2] = v.z; vv[q][3] = v.w;
      } else {
#pragma unroll
        for (int e = 0; e < 4; ++e)
          vv[q][e] = fb[(size_t)(cb + q) * 2500 + min(p + e, 2499)];
      }
    }
#pragma unroll
    for (int pp = 0; pp < 4; ++pp) {
      ushort4 pk;
      pk.x = f2bf(vv[0][pp]); pk.y = f2bf(vv[1][pp]);
      pk.z = f2bf(vv[2][pp]); pk.w = f2bf(vv[3][pp]);
      *(ushort4*)&sT[(pq * 4 + pp) * 132 + cb] = pk;
    }
  }
  __syncthreads();
#pragma unroll
  for (int q2 = 0; q2 < 2; ++q2) {
    int u = tid + q2 * 256;
    int pr = u >> 2, ch = u & 3;
    int gp = pos0 + pr;
    if (gp >= 2500) continue;
    int i = gp / 50, j = gp - i * 50;
    char* dst = featT2 + (size_t)((b * 52 + i + 1) * 52 + (j + 1)) * FT_POS_B
              + (g * 4 + ch) * 64;
    const uint4* src = (const uint4*)&sT[pr * 132 + ch * 32];
    uint4 a0 = src[0], a1 = src[1], a2 = src[2], a3 = src[3];
    *(uint4*)(dst)      = a0;
    *(uint4*)(dst + 16) = a1;
    *(uint4*)(dst + 32) = a2;
    *(uint4*)(dst + 48) = a3;
  }
}

// ---------- 2a. compose partials (+ zero mx/accum: replaces memset dispatch) ----------
__global__ __launch_bounds__(128) void k_weff1(const float* __restrict__ w1,
                                               const float* __restrict__ wc,
                                               const float* __restrict__ wb,
                                               float* __restrict__ part,
                                               unsigned* __restrict__ zbuf) {
  const int t = threadIdx.x;
  if (blockIdx.x == 0 && blockIdx.y == 0) {   // zero mx(256)+accum(8) dwords
    for (int idx = t; idx < 264; idx += 128) zbuf[idx] = 0u;
  }
  __shared__ float sW[48][64];
  const int kmem = blockIdx.x * 128 + t;
  const int cz = blockIdx.y;
#pragma unroll
  for (int q = 0; q < 24; ++q) {
    int idx = t + q * 128;
    int co = idx >> 6, cl = idx & 63;
    int c = cz * 64 + cl;
    float v = 0.f;
    if (co < 9) v = wc[co * 512 + c];
    else if (co < 45) v = wb[(co - 9) * 512 + c];
    sW[co][cl] = v;
  }
  __syncthreads();
  float acc[48];
#pragma unroll
  for (int co = 0; co < 48; ++co) acc[co] = 0.f;
  const float* w1p = w1 + (size_t)(cz * 64) * 4608 + kmem;
  for (int c4 = 0; c4 < 64; c4 += 4) {
    float f0 = w1p[(size_t)(c4 + 0) * 4608];
    float f1 = w1p[(size_t)(c4 + 1) * 4608];
    float f2 = w1p[(size_t)(c4 + 2) * 4608];
    float f3 = w1p[(size_t)(c4 + 3) * 4608];
#pragma unroll
    for (int co = 0; co < 48; ++co) {
      float4 wv = *(const float4*)&sW[co][c4];
      acc[co] += wv.x * f0 + wv.y * f1 + wv.z * f2 + wv.w * f3;
    }
  }
  float* dst = part + (size_t)cz * 221184 + kmem;
#pragma unroll
  for (int co = 0; co < 48; ++co) dst[(size_t)co * 4608] = acc[co];
}

// ---------- 2b. reduce partials -> W2 records (bf16); blocks >=1080 do bias ----------
__global__ __launch_bounds__(256) void k_weff2(const float* __restrict__ part,
                                               unsigned short* __restrict__ w2,
                                               const float* __restrict__ wc,
                                               const float* __restrict__ wb,
                                               const float* __restrict__ b1,
                                               const float* __restrict__ bc,
                                               const float* __restrict__ bbx,
                                               float* __restrict__ bias_eff) {
  if (blockIdx.x >= 1080) {                  // bias_eff[co] = b_head + whead·b1
    int co = blockIdx.x - 1080;
    int l = threadIdx.x;
    if (l >= 64) return;
    float s = 0.f;
#pragma unroll
    for (int q = 0; q < 8; ++q) {
      int c = q * 64 + l;
      float wv = co < 9 ? wc[co * 512 + c] : (co < 45 ? wb[(co - 9) * 512 + c] : 0.f);
      s += wv * b1[c];
    }
    for (int o = 32; o; o >>= 1) s += __shfl_down(s, o, 64);
    if (l == 0)
      bias_eff[co] = s + (co < 9 ? bc[co] : (co < 45 ? bbx[co - 9] : 0.f));
    return;
  }
  int idx = blockIdx.x * 256 + threadIdx.x;   // < 276480 = 16*9*48*40
  int c = idx / 17280;  int r = idx - c * 17280;
  int tap = r / 1920;   int r2 = r - tap * 1920;
  int co = r2 / 40;     int e = r2 - co * 40;
  float s = 0.f;
  if (e < 32) {
    int ci = c * 32 + e;
    const float* p = part + (size_t)co * 4608 + ci * 9 + tap;
#pragma unroll
    for (int cz = 0; cz < 8; ++cz) s += p[(size_t)cz * 221184];
  }
  w2[idx] = f2bf(s);
}

// ---------- 3. per-(b,gt) max IoU (k_loss recomputes IoU bitwise-identically) ----------
__global__ __launch_bounds__(256) void k_iou(const float* __restrict__ gt_boxes,
                                             unsigned* __restrict__ mx) {
  int b = blockIdx.y;
  int n = blockIdx.x * 256 + threadIdx.x;
  float lm[16];
#pragma unroll
  for (int m = 0; m < 16; ++m) lm[m] = 0.f;
  if (n < 22500) {
    float ax1, ay1, ax2, ay2;
    anchor_strict(n, ax1, ay1, ax2, ay2);
    float aarea = __fmul_rn(__fsub_rn(ax2, ax1), __fsub_rn(ay2, ay1));
#pragma unroll
    for (int m = 0; m < 16; ++m)
      lm[m] = iou_strict(ax1, ay1, ax2, ay2, aarea, gt_boxes + (b * 16 + m) * 4);
  }
  __shared__ float red[4][16];
#pragma unroll
  for (int m = 0; m < 16; ++m) {
    float v = lm[m];
    for (int o = 32; o; o >>= 1) v = fmaxf(v, __shfl_down(v, o, 64));
    if ((threadIdx.x & 63) == 0) red[threadIdx.x >> 6][m] = v;
  }
  __syncthreads();
  if (threadIdx.x < 16) {
    float v = fmaxf(fmaxf(red[0][threadIdx.x], red[1][threadIdx.x]),
                    fmaxf(red[2][threadIdx.x], red[3][threadIdx.x]));
    atomicMax(mx + b * 16 + threadIdx.x, __float_as_uint(v));
  }
}

// ---------- 4. direct conv+head: spatial tiles, all 9 taps from LDS ----------
__global__ __launch_bounds__(256) void k_conv(const char* __restrict__ featT2,
                                              const char* __restrict__ w2,
                                              const float* __restrict__ beff,
                                              float* __restrict__ oh) {
  __shared__ __align__(16) char sF[2][19456];   // 225*80=18000 used; 18*1024 staged
  __shared__ __align__(16) char sA[2][34816];   // 9*48*80=34560; 34*1024 staged
  const int tid = threadIdx.x, lane = tid & 63, w = tid >> 6;
  const int bx = blockIdx.x;
  const int b = bx >> 4, tl = bx & 15, tr = tl >> 2, tc = tl & 3;
  const int i0 = tr * 13 - (tr == 3 ? 1 : 0);   // {0,13,26,38}
  const int TI = (tr >= 2) ? 12 : 13;
  const int j0 = tc * 13 - (tc == 3 ? 1 : 0);
  const int TJ = (tc >= 2) ? 12 : 13;
  const int TJ2 = TJ + 2;
  const int mcount = TI * TJ;
  const int pieces = (TI + 2) * TJ2 * 5;        // LDS 16B pieces per chunk

  // sF staging: LDS piece pi -> (pos, pc); pc==4 is the LDS pad piece, staged
  // as a duplicate of global piece 3 (packed 64 B records) — never read.
  const char* srcF[5];
#pragma unroll
  for (int k = 0; k < 5; ++k) {
    int s = w * 5 + k;
    int pi = s * 64 + lane;
    if (pi >= pieces) pi = pieces - 1;
    int pos = pi / 5, pc = pi - pos * 5;
    if (pc > 3) pc = 3;
    int hi = pos / TJ2, hj = pos - hi * TJ2;
    srcF[k] = featT2 + (size_t)((b * 52 + i0 + hi) * 52 + (j0 + hj)) * FT_POS_B + pc * 16;
  }
  int idxB[3];
#pragma unroll
  for (int bf = 0; bf < 3; ++bf) {
    int p = (w * 3 + bf) * 16 + (lane & 15);
    if (p >= mcount) p = mcount - 1;
    int di = p / TJ, dj = p - di * TJ;
    idxB[bf] = (di * TJ2 + dj) * 80 + (lane >> 4) * 16;
  }
  const int aoff = (lane & 15) * 80 + (lane >> 4) * 16;
  int toff[9];
#pragma unroll
  for (int tp = 0; tp < 9; ++tp) toff[tp] = ((tp / 3) * TJ2 + (tp % 3)) * 80;

  f32x4 acc[3][3] = {};

  auto stage = [&](int c, int pb) {
#pragma unroll
    for (int k = 0; k < 5; ++k) {
      int s = w * 5 + k;
      if (s < 18) gl_lds16(srcF[k] + (size_t)c * 64, sF[pb] + s * 1024);
    }
#pragma unroll
    for (int k = 0; k < 9; ++k) {
      int s = w + 4 * k;
      if (s < 34)
        gl_lds16(w2 + (size_t)c * W2_CHUNK_B + s * 1024 + lane * 16, sA[pb] + s * 1024);
    }
  };

  stage(0, 0);
  __builtin_amdgcn_s_waitcnt(0);
  __syncthreads();

  for (int c = 0; c < 16; ++c) {
    int pb = c & 1;
    if (c < 15) stage(c + 1, pb ^ 1);
    const char* fA = sA[pb];
    const char* fB = sF[pb];
#pragma unroll
    for (int tp = 0; tp < 9; ++tp) {
      bf16x8 av[3], bv[3];
#pragma unroll
      for (int cf = 0; cf < 3; ++cf)
        av[cf] = *(const bf16x8*)(fA + tp * 3840 + cf * 1280 + aoff);
#pragma unroll
      for (int bf = 0; bf < 3; ++bf)
        bv[bf] = *(const bf16x8*)(fB + idxB[bf] + toff[tp]);
#pragma unroll
      for (int cf = 0; cf < 3; ++cf)
#pragma unroll
        for (int bf = 0; bf < 3; ++bf)
          acc[cf][bf] = __builtin_amdgcn_mfma_f32_16x16x32_bf16(av[cf], bv[bf], acc[cf][bf], 0, 0, 0);
    }
    __builtin_amdgcn_s_waitcnt(0);
    __syncthreads();
  }

  f32x4 bias[3];
#pragma unroll
  for (int cf = 0; cf < 3; ++cf)
    bias[cf] = *(const f32x4*)(beff + cf * 16 + (lane >> 4) * 4);
#pragma unroll
  for (int bf = 0; bf < 3; ++bf) {
    int p = (w * 3 + bf) * 16 + (lane & 15);
    if (p >= mcount) continue;
    int di = p / TJ, dj = p - di * TJ;
    int gm = (b * 50 + i0 + di) * 50 + (j0 + dj);
#pragma unroll
    for (int cf = 0; cf < 3; ++cf) {
      f32x4 v = acc[cf][bf];
#pragma unroll
      for (int r = 0; r < 4; ++r) v[r] += bias[cf][r];
      *(f32x4*)(oh + (size_t)gm * 48 + cf * 16 + (lane >> 4) * 4) = v;
    }
  }
}

// ---------- 5. loss pass: recompute IoU (strict), loss sums, proposals ----------
__global__ __launch_bounds__(256) void k_loss(const float* __restrict__ gt_boxes,
                                              const unsigned* __restrict__ mxbuf,
                                              const float* __restrict__ oh,
                                              float* __restrict__ accum,
                                              float* __restrict__ dout) {
  int b = blockIdx.y;
  int n = blockIdx.x * 256 + threadIdx.x;
  float s_np = 0.f, s_reg = 0.f, s_pos = 0.f, s_nc = 0.f, s_nl = 0.f;
  if (n < 22500) {
    float ax1, ay1, ax2, ay2;
    anchor_strict(n, ax1, ay1, ax2, ay2);
    float aarea = __fmul_rn(__fsub_rn(ax2, ax1), __fsub_rn(ay2, ay1));
    float acx = (ax1 + ax2) * 0.5f, acy = (ay1 + ay2) * 0.5f;
    float aw = fmaxf(ax2 - ax1, 1e-6f), ah = fmaxf(ay2 - ay1, 1e-6f);
    int ii = n / 450, rem = n - ii * 450, jj = rem / 9, a = rem - jj * 9;
    const float* row = oh + ((size_t)(b * 2500 + ii * 50 + jj)) * 48;
    float logit = row[a];
    float p0 = row[9 + a * 4], p1 = row[10 + a * 4];
    float p2 = row[11 + a * 4], p3 = row[12 + a * 4];
    int npos = 0;
    bool allneg = true;
#pragma unroll
    for (int m = 0; m < 16; ++m) {
      const float* g = gt_boxes + (b * 16 + m) * 4;
      float iou = iou_strict(ax1, ay1, ax2, ay2, aarea, g);
      float mxv = __uint_as_float(mxbuf[b * 16 + m]);
      bool pos = ((iou == mxv) && (mxv > 0.f)) || (iou > 0.7f);
      if (iou >= 0.3f) allneg = false;
      if (pos) {
        ++npos;
        float gx1 = g[0] * 0.0625f, gy1 = g[1] * 0.0625f;
        float gx2 = g[2] * 0.0625f, gy2 = g[3] * 0.0625f;
        float gcx = (gx1 + gx2) * 0.5f, gcy = (gy1 + gy2) * 0.5f;
        float gw = fmaxf(gx2 - gx1, 1e-6f), gh = fmaxf(gy2 - gy1, 1e-6f);
        float tx = (gcx - acx) / aw, ty = (gcy - acy) / ah;
        float twv = logf(gw / aw), thv = logf(gh / ah);
        s_reg += sl1(tx - p0) + sl1(ty - p1) + sl1(twv - p2) + sl1(thv - p3);
      }
    }
    s_np = (float)npos;
    s_pos = (float)npos * softplus_f(-logit);
    if (allneg) { s_nc = 1.f; s_nl = softplus_f(logit); }
    float pcx = acx + p0 * aw, pcy = acy + p1 * ah;
    float pw = aw * expf(p2), ph = ah * expf(p3);
    float* o = dout + 1 + ((size_t)b * 22500 + n) * 4;
    o[0] = pcx - pw * 0.5f;
    o[1] = pcy - ph * 0.5f;
    o[2] = pcx + pw * 0.5f;
    o[3] = pcy + ph * 0.5f;
  }
  float vals[5] = {s_np, s_reg, s_pos, s_nc, s_nl};
  __shared__ float red[4][5];
#pragma unroll
  for (int q = 0; q < 5; ++q) {
    float v = vals[q];
    for (int o = 32; o; o >>= 1) v += __shfl_down(v, o, 64);
    if ((threadIdx.x & 63) == 0) red[threadIdx.x >> 6][q] = v;
  }
  __syncthreads();
  if (threadIdx.x < 5) {
    float v = red[0][threadIdx.x] + red[1][threadIdx.x] +
              red[2][threadIdx.x] + red[3][threadIdx.x];
    atomicAdd(accum + threadIdx.x, v);
  }
}

// ---------- 6. finalize ----------
__global__ void k_fin(const float* __restrict__ accum, float* __restrict__ dout) {
  if (threadIdx.x == 0 && blockIdx.x == 0) {
    float np = fmaxf(accum[0], 1.f);
    float nn = fmaxf(accum[3], 1.f);
    float loss = 0.5f * (accum[2] / np + accum[4] / nn) + 5.f * (accum[1] / (4.f * np));
    dout[0] = loss;
  }
}

// ---------- launch ----------
extern "C" void kernel_launch(void* const* d_in, const int* in_sizes, int n_in,
                              void* d_out, int out_size, void* d_ws, size_t ws_size,
                              hipStream_t stream) {
  const float* features = (const float*)d_in[0];
  const float* gt_boxes = (const float*)d_in[1];
  const float* w1    = (const float*)d_in[2];
  const float* b1    = (const float*)d_in[3];
  const float* w_cls = (const float*)d_in[4];
  const float* b_cls = (const float*)d_in[5];
  const float* w_box = (const float*)d_in[6];
  const float* b_box = (const float*)d_in[7];
  float* out = (float*)d_out;
  char* ws = (char*)d_ws;

  // ws layout (featT2 packed: 16*52*52*1024 = 44,302,336 B)
  char*           featT2 = ws;                                  // 44,302,336 B
  unsigned short* w2     = (unsigned short*)(ws + 44302336);    //    552,960 B
  float*          wpart  = (float*)(ws + 44855296);             //  7,077,888 B
  float*          oh     = (float*)(ws + 51933184);             //  7,680,000 B
  float*          beff   = (float*)(ws + 59613184);             //        192 B
  unsigned*       mx     = (unsigned*)(ws + 59613376);          //      1,024 B
  float*          accum  = (float*)(ws + 59614400);             //         32 B

  k_featT<<<dim3(21, 4, 16), 256, 0, stream>>>(features, featT2);
  k_weff1<<<dim3(36, 8), 128, 0, stream>>>(w1, w_cls, w_box, wpart, mx);
  k_weff2<<<1128, 256, 0, stream>>>(wpart, w2, w_cls, w_box, b1, b_cls, b_box, beff);
  k_iou<<<dim3(88, 16), 256, 0, stream>>>(gt_boxes, mx);
  k_conv<<<256, 256, 0, stream>>>(featT2, (const char*)w2, beff, oh);
  k_loss<<<dim3(88, 16), 256, 0, stream>>>(gt_boxes, mx, oh, accum, out);
  k_fin<<<1, 64, 0, stream>>>(accum, out);
}

// Round 9
// 261.776 us; speedup vs baseline: 2.3410x; 1.0310x over previous
//
#include <hip/hip_runtime.h>
#include <hip/hip_bf16.h>
#include <stdint.h>

using bf16x8 = __attribute__((ext_vector_type(8))) __bf16;
using f32x4  = __attribute__((ext_vector_type(4))) float;

// featT2 layout (R9: CHUNK-MAJOR): featT2[chunk 16][img 16][pos 52*52][64 B].
// pos = i*52+j, row/col 0,51 = zero borders. All data bytes written every call
// by k_featT (interior tiles + border tile); no memset. Chunk-major makes both
// k_featT writes (4 KB contiguous per wave) and k_conv's per-chunk staging
// (~3 KB contiguous row segments) DRAM-page friendly.
#define FT_CHUNK_STRIDE 2768896   // 16 img * 2704 pos * 64 B
// W2 layout: [ci-chunk 16][tap 9][co 48][80 B record] (small, stays padded)
#define W2_CHUNK_B 34560

// ---------- helpers ----------
__device__ __forceinline__ unsigned short f2bf(float f) {
  union { float f; unsigned u; } x; x.f = f;
  unsigned r = x.u + 0x7fffu + ((x.u >> 16) & 1u);   // RNE
  return (unsigned short)(r >> 16);
}

__device__ __forceinline__ void gl_lds16(const void* g, void* l) {
  __builtin_amdgcn_global_load_lds(
      (const __attribute__((address_space(1))) void*)g,
      (__attribute__((address_space(3))) void*)l, 16, 0, 0);
}

__device__ __forceinline__ float sl1(float d) {
  float ad = fabsf(d);
  return ad < 1.f ? 0.5f * d * d : ad - 0.5f;
}
__device__ __forceinline__ float softplus_f(float x) {
  return fmaxf(x, 0.f) + log1pf(expf(-fabsf(x)));
}

// strict-fp anchor + IoU: identical bits in weff2-iou and k_loss (no contraction
// possible through __f*_rn intrinsics) so the (iou == max) test is exact.
__device__ __forceinline__ void anchor_strict(int n, float& ax1, float& ay1,
                                              float& ax2, float& ay2) {
  int ii = n / 450;
  int rem = n - ii * 450;
  int jj = rem / 9;
  int a  = rem - jj * 9;
  const float SC[3] = {2.f, 4.f, 6.f};
  const float RA[3] = {0.5f, 1.f, 1.5f};
  float w = __fmul_rn(SC[a % 3], RA[a / 3]);
  float h = SC[a % 3];
  float cx = __fadd_rn((float)ii, 0.5f);
  float cy = __fadd_rn((float)jj, 0.5f);
  float wh = __fmul_rn(w, 0.5f), hh = __fmul_rn(h, 0.5f);
  ax1 = fminf(fmaxf(__fsub_rn(cx, wh), 0.f), 50.f);
  ax2 = fminf(fmaxf(__fadd_rn(cx, wh), 0.f), 50.f);
  ay1 = fminf(fmaxf(__fsub_rn(cy, hh), 0.f), 50.f);
  ay2 = fminf(fmaxf(__fadd_rn(cy, hh), 0.f), 50.f);
}
__device__ __forceinline__ float iou_strict(float ax1, float ay1, float ax2, float ay2,
                                            float aarea, const float* __restrict__ g) {
  float gx1 = __fmul_rn(g[0], 0.0625f), gy1 = __fmul_rn(g[1], 0.0625f);
  float gx2 = __fmul_rn(g[2], 0.0625f), gy2 = __fmul_rn(g[3], 0.0625f);
  float ix1 = fmaxf(ax1, gx1), iy1 = fmaxf(ay1, gy1);
  float ix2 = fminf(ax2, gx2), iy2 = fminf(ay2, gy2);
  float inter = __fmul_rn(fmaxf(__fsub_rn(ix2, ix1), 0.f),
                          fmaxf(__fsub_rn(iy2, iy1), 0.f));
  float garea = __fmul_rn(__fsub_rn(gx2, gx1), __fsub_rn(gy2, gy1));
  float denom = __fadd_rn(__fsub_rn(__fadd_rn(aarea, garea), inter), 1e-8f);
  return __fdiv_rn(inter, denom);
}

// ---------- 1. features NCHW fp32 -> chunk-major packed bf16 (LDS transpose) ----------
// grid (21, 4, 16): x = 128-pos tile (20 = border-zero), y = 128-ci group, z = image.
// Read: lanes along pos -> wave-load = 2 x 512 B contiguous.
// Write: consecutive threads = consecutive pos in ONE chunk plane -> 4 KB
// contiguous per wave (R8 was 256 B segments at 1 KB stride -> page-bound).
__global__ __launch_bounds__(256) void k_featT(const float* __restrict__ feat,
                                               char* __restrict__ featT2) {
  const int tile = blockIdx.x;
  const int g    = blockIdx.y;            // ci group: chunks g*4..g*4+3
  const int b    = blockIdx.z;
  const int tid  = threadIdx.x;
  if (tile == 20) {                       // border: zero 204 positions' chunks
    uint4 z = {0, 0, 0, 0};
    for (int u = tid; u < 204 * 4; u += 256) {
      int p = u & 255; if (p >= 204) p -= 204;     // u%204 without div
      int c4 = u / 204;
      int ip, jp;
      if (p < 52)       { ip = 0;       jp = p; }
      else if (p < 104) { ip = 51;      jp = p - 52; }
      else if (p < 154) { ip = p - 103; jp = 0; }
      else              { ip = p - 153; jp = 51; }
      char* dst = featT2 + (size_t)(g * 4 + c4) * FT_CHUNK_STRIDE
                + (size_t)(b * 2704 + ip * 52 + jp) * 64;
      *(uint4*)(dst)      = z;
      *(uint4*)(dst + 16) = z;
      *(uint4*)(dst + 32) = z;
      *(uint4*)(dst + 48) = z;
    }
    return;
  }
  __shared__ __align__(16) unsigned short sT[128 * 132];  // row stride 264 B
  const int pos0 = tile * 128;
  const float* fb = feat + (size_t)b * 1280000 + (size_t)(g * 128) * 2500;
  const int pq = tid & 31;                // pos quad: pos0 + pq*4 .. +3
  const int rg = tid >> 5;                // ci row-group (4 rows), 0..7
  const int p  = pos0 + pq * 4;
#pragma unroll
  for (int it = 0; it < 4; ++it) {
    int cb = it * 32 + rg * 4;            // ci within group
    float vv[4][4];
#pragma unroll
    for (int q = 0; q < 4; ++q) {
      const float* src = fb + (size_t)(cb + q) * 2500 + p;
      if (p + 3 < 2500) {
        float4 v = *(const float4*)src;
        vv[q][0] = v.x; vv[q][1] = v.y; vv[q][2] = v.z; vv[q][3] = v.w;
      } else {
#pragma unroll
        for (int e = 0; e < 4; ++e)
          vv[q][e] = fb[(size_t)(cb + q) * 2500 + min(p + e, 2499)];
      }
    }
#pragma unroll
    for (int pp = 0; pp < 4; ++pp) {
      ushort4 pk;
      pk.x = f2bf(vv[0][pp]); pk.y = f2bf(vv[1][pp]);
      pk.z = f2bf(vv[2][pp]); pk.w = f2bf(vv[3][pp]);
      *(ushort4*)&sT[(pq * 4 + pp) * 132 + cb] = pk;
    }
  }
  __syncthreads();
#pragma unroll
  for (int q2 = 0; q2 < 2; ++q2) {
    int u = tid + q2 * 256;
    int ch = u >> 7, pr = u & 127;        // consecutive threads -> consecutive pos
    int gp = pos0 + pr;
    if (gp >= 2500) continue;
    int i = gp / 50, j = gp - i * 50;
    char* dst = featT2 + (size_t)(g * 4 + ch) * FT_CHUNK_STRIDE
              + (size_t)(b * 2704 + (i + 1) * 52 + (j + 1)) * 64;
    const uint4* src = (const uint4*)&sT[pr * 132 + ch * 32];
    uint4 a0 = src[0], a1 = src[1], a2 = src[2], a3 = src[3];
    *(uint4*)(dst)      = a0;
    *(uint4*)(dst + 16) = a1;
    *(uint4*)(dst + 32) = a2;
    *(uint4*)(dst + 48) = a3;
  }
}

// ---------- 2a. compose partials (+ zero mx/accum: replaces memset dispatch) ----------
__global__ __launch_bounds__(128) void k_weff1(const float* __restrict__ w1,
                                               const float* __restrict__ wc,
                                               const float* __restrict__ wb,
                                               float* __restrict__ part,
                                               unsigned* __restrict__ zbuf) {
  const int t = threadIdx.x;
  if (blockIdx.x == 0 && blockIdx.y == 0) {   // zero mx(256)+accum(8) dwords
    for (int idx = t; idx < 264; idx += 128) zbuf[idx] = 0u;
  }
  __shared__ float sW[48][64];
  const int kmem = blockIdx.x * 128 + t;
  const int cz = blockIdx.y;
#pragma unroll
  for (int q = 0; q < 24; ++q) {
    int idx = t + q * 128;
    int co = idx >> 6, cl = idx & 63;
    int c = cz * 64 + cl;
    float v = 0.f;
    if (co < 9) v = wc[co * 512 + c];
    else if (co < 45) v = wb[(co - 9) * 512 + c];
    sW[co][cl] = v;
  }
  __syncthreads();
  float acc[48];
#pragma unroll
  for (int co = 0; co < 48; ++co) acc[co] = 0.f;
  const float* w1p = w1 + (size_t)(cz * 64) * 4608 + kmem;
  for (int c4 = 0; c4 < 64; c4 += 4) {
    float f0 = w1p[(size_t)(c4 + 0) * 4608];
    float f1 = w1p[(size_t)(c4 + 1) * 4608];
    float f2 = w1p[(size_t)(c4 + 2) * 4608];
    float f3 = w1p[(size_t)(c4 + 3) * 4608];
#pragma unroll
    for (int co = 0; co < 48; ++co) {
      float4 wv = *(const float4*)&sW[co][c4];
      acc[co] += wv.x * f0 + wv.y * f1 + wv.z * f2 + wv.w * f3;
    }
  }
  float* dst = part + (size_t)cz * 221184 + kmem;
#pragma unroll
  for (int co = 0; co < 48; ++co) dst[(size_t)co * 4608] = acc[co];
}

// ---------- 2b. blocks <1080: reduce partials -> W2; 1080..1127: bias;
//              blocks >=1128: per-(b,gt) max IoU (folded k_iou dispatch) ----------
__global__ __launch_bounds__(256) void k_weff2(const float* __restrict__ part,
                                               unsigned short* __restrict__ w2,
                                               const float* __restrict__ wc,
                                               const float* __restrict__ wb,
                                               const float* __restrict__ b1,
                                               const float* __restrict__ bc,
                                               const float* __restrict__ bbx,
                                               float* __restrict__ bias_eff,
                                               const float* __restrict__ gt_boxes,
                                               unsigned* __restrict__ mx) {
  if (blockIdx.x >= 1128) {                  // IoU max pass
    int q = blockIdx.x - 1128;               // 0..1407
    int b = q / 88, nb = q - b * 88;
    int n = nb * 256 + threadIdx.x;
    float lm[16];
#pragma unroll
    for (int m = 0; m < 16; ++m) lm[m] = 0.f;
    if (n < 22500) {
      float ax1, ay1, ax2, ay2;
      anchor_strict(n, ax1, ay1, ax2, ay2);
      float aarea = __fmul_rn(__fsub_rn(ax2, ax1), __fsub_rn(ay2, ay1));
#pragma unroll
      for (int m = 0; m < 16; ++m)
        lm[m] = iou_strict(ax1, ay1, ax2, ay2, aarea, gt_boxes + (b * 16 + m) * 4);
    }
    __shared__ float red[4][16];
#pragma unroll
    for (int m = 0; m < 16; ++m) {
      float v = lm[m];
      for (int o = 32; o; o >>= 1) v = fmaxf(v, __shfl_down(v, o, 64));
      if ((threadIdx.x & 63) == 0) red[threadIdx.x >> 6][m] = v;
    }
    __syncthreads();
    if (threadIdx.x < 16) {
      float v = fmaxf(fmaxf(red[0][threadIdx.x], red[1][threadIdx.x]),
                      fmaxf(red[2][threadIdx.x], red[3][threadIdx.x]));
      atomicMax(mx + b * 16 + threadIdx.x, __float_as_uint(v));
    }
    return;
  }
  if (blockIdx.x >= 1080) {                  // bias_eff[co] = b_head + whead·b1
    int co = blockIdx.x - 1080;
    int l = threadIdx.x;
    if (l >= 64) return;
    float s = 0.f;
#pragma unroll
    for (int q = 0; q < 8; ++q) {
      int c = q * 64 + l;
      float wv = co < 9 ? wc[co * 512 + c] : (co < 45 ? wb[(co - 9) * 512 + c] : 0.f);
      s += wv * b1[c];
    }
    for (int o = 32; o; o >>= 1) s += __shfl_down(s, o, 64);
    if (l == 0)
      bias_eff[co] = s + (co < 9 ? bc[co] : (co < 45 ? bbx[co - 9] : 0.f));
    return;
  }
  int idx = blockIdx.x * 256 + threadIdx.x;   // < 276480 = 16*9*48*40
  int c = idx / 17280;  int r = idx - c * 17280;
  int tap = r / 1920;   int r2 = r - tap * 1920;
  int co = r2 / 40;     int e = r2 - co * 40;
  float s = 0.f;
  if (e < 32) {
    int ci = c * 32 + e;
    const float* p = part + (size_t)co * 4608 + ci * 9 + tap;
#pragma unroll
    for (int cz = 0; cz < 8; ++cz) s += p[(size_t)cz * 221184];
  }
  w2[idx] = f2bf(s);
}

// ---------- 3. direct conv+head: spatial tiles, all 9 taps from LDS ----------
__global__ __launch_bounds__(256) void k_conv(const char* __restrict__ featT2,
                                              const char* __restrict__ w2,
                                              const float* __restrict__ beff,
                                              float* __restrict__ oh) {
  __shared__ __align__(16) char sF[2][19456];   // 225*80=18000 used; 18*1024 staged
  __shared__ __align__(16) char sA[2][34816];   // 9*48*80=34560; 34*1024 staged
  const int tid = threadIdx.x, lane = tid & 63, w = tid >> 6;
  const int bx = blockIdx.x;
  const int b = bx >> 4, tl = bx & 15, tr = tl >> 2, tc = tl & 3;
  const int i0 = tr * 13 - (tr == 3 ? 1 : 0);   // {0,13,26,38}
  const int TI = (tr >= 2) ? 12 : 13;
  const int j0 = tc * 13 - (tc == 3 ? 1 : 0);
  const int TJ = (tc >= 2) ? 12 : 13;
  const int TJ2 = TJ + 2;
  const int mcount = TI * TJ;
  const int pieces = (TI + 2) * TJ2 * 5;        // LDS 16B pieces per chunk

  // sF staging: LDS piece pi -> (pos, pc); pc==4 is the LDS pad piece, staged
  // as a duplicate of piece 3 — never read. Chunk-major: stage adds c*stride.
  const char* srcF[5];
#pragma unroll
  for (int k = 0; k < 5; ++k) {
    int s = w * 5 + k;
    int pi = s * 64 + lane;
    if (pi >= pieces) pi = pieces - 1;
    int pos = pi / 5, pc = pi - pos * 5;
    if (pc > 3) pc = 3;
    int hi = pos / TJ2, hj = pos - hi * TJ2;
    srcF[k] = featT2 + (size_t)(b * 2704 + (i0 + hi) * 52 + (j0 + hj)) * 64 + pc * 16;
  }
  int idxB[3];
#pragma unroll
  for (int bf = 0; bf < 3; ++bf) {
    int p = (w * 3 + bf) * 16 + (lane & 15);
    if (p >= mcount) p = mcount - 1;
    int di = p / TJ, dj = p - di * TJ;
    idxB[bf] = (di * TJ2 + dj) * 80 + (lane >> 4) * 16;
  }
  const int aoff = (lane & 15) * 80 + (lane >> 4) * 16;
  int toff[9];
#pragma unroll
  for (int tp = 0; tp < 9; ++tp) toff[tp] = ((tp / 3) * TJ2 + (tp % 3)) * 80;

  f32x4 acc[3][3] = {};

  auto stage = [&](int c, int pb) {
    size_t coff = (size_t)c * FT_CHUNK_STRIDE;
#pragma unroll
    for (int k = 0; k < 5; ++k) {
      int s = w * 5 + k;
      if (s < 18) gl_lds16(srcF[k] + coff, sF[pb] + s * 1024);
    }
#pragma unroll
    for (int k = 0; k < 9; ++k) {
      int s = w + 4 * k;
      if (s < 34)
        gl_lds16(w2 + (size_t)c * W2_CHUNK_B + s * 1024 + lane * 16, sA[pb] + s * 1024);
    }
  };

  stage(0, 0);
  __builtin_amdgcn_s_waitcnt(0);
  __syncthreads();

  for (int c = 0; c < 16; ++c) {
    int pb = c & 1;
    if (c < 15) stage(c + 1, pb ^ 1);
    const char* fA = sA[pb];
    const char* fB = sF[pb];
#pragma unroll
    for (int tp = 0; tp < 9; ++tp) {
      bf16x8 av[3], bv[3];
#pragma unroll
      for (int cf = 0; cf < 3; ++cf)
        av[cf] = *(const bf16x8*)(fA + tp * 3840 + cf * 1280 + aoff);
#pragma unroll
      for (int bf = 0; bf < 3; ++bf)
        bv[bf] = *(const bf16x8*)(fB + idxB[bf] + toff[tp]);
#pragma unroll
      for (int cf = 0; cf < 3; ++cf)
#pragma unroll
        for (int bf = 0; bf < 3; ++bf)
          acc[cf][bf] = __builtin_amdgcn_mfma_f32_16x16x32_bf16(av[cf], bv[bf], acc[cf][bf], 0, 0, 0);
    }
    __builtin_amdgcn_s_waitcnt(0);
    __syncthreads();
  }

  f32x4 bias[3];
#pragma unroll
  for (int cf = 0; cf < 3; ++cf)
    bias[cf] = *(const f32x4*)(beff + cf * 16 + (lane >> 4) * 4);
#pragma unroll
  for (int bf = 0; bf < 3; ++bf) {
    int p = (w * 3 + bf) * 16 + (lane & 15);
    if (p >= mcount) continue;
    int di = p / TJ, dj = p - di * TJ;
    int gm = (b * 50 + i0 + di) * 50 + (j0 + dj);
#pragma unroll
    for (int cf = 0; cf < 3; ++cf) {
      f32x4 v = acc[cf][bf];
#pragma unroll
      for (int r = 0; r < 4; ++r) v[r] += bias[cf][r];
      *(f32x4*)(oh + (size_t)gm * 48 + cf * 16 + (lane >> 4) * 4) = v;
    }
  }
}

// ---------- 4. loss pass: recompute IoU (strict), loss sums, proposals ----------
__global__ __launch_bounds__(256) void k_loss(const float* __restrict__ gt_boxes,
                                              const unsigned* __restrict__ mxbuf,
                                              const float* __restrict__ oh,
                                              float* __restrict__ accum,
                                              float* __restrict__ dout) {
  int b = blockIdx.y;
  int n = blockIdx.x * 256 + threadIdx.x;
  float s_np = 0.f, s_reg = 0.f, s_pos = 0.f, s_nc = 0.f, s_nl = 0.f;
  if (n < 22500) {
    float ax1, ay1, ax2, ay2;
    anchor_strict(n, ax1, ay1, ax2, ay2);
    float aarea = __fmul_rn(__fsub_rn(ax2, ax1), __fsub_rn(ay2, ay1));
    float acx = (ax1 + ax2) * 0.5f, acy = (ay1 + ay2) * 0.5f;
    float aw = fmaxf(ax2 - ax1, 1e-6f), ah = fmaxf(ay2 - ay1, 1e-6f);
    int ii = n / 450, rem = n - ii * 450, jj = rem / 9, a = rem - jj * 9;
    const float* row = oh + ((size_t)(b * 2500 + ii * 50 + jj)) * 48;
    float logit = row[a];
    float p0 = row[9 + a * 4], p1 = row[10 + a * 4];
    float p2 = row[11 + a * 4], p3 = row[12 + a * 4];
    int npos = 0;
    bool allneg = true;
#pragma unroll
    for (int m = 0; m < 16; ++m) {
      const float* g = gt_boxes + (b * 16 + m) * 4;
      float iou = iou_strict(ax1, ay1, ax2, ay2, aarea, g);
      float mxv = __uint_as_float(mxbuf[b * 16 + m]);
      bool pos = ((iou == mxv) && (mxv > 0.f)) || (iou > 0.7f);
      if (iou >= 0.3f) allneg = false;
      if (pos) {
        ++npos;
        float gx1 = g[0] * 0.0625f, gy1 = g[1] * 0.0625f;
        float gx2 = g[2] * 0.0625f, gy2 = g[3] * 0.0625f;
        float gcx = (gx1 + gx2) * 0.5f, gcy = (gy1 + gy2) * 0.5f;
        float gw = fmaxf(gx2 - gx1, 1e-6f), gh = fmaxf(gy2 - gy1, 1e-6f);
        float tx = (gcx - acx) / aw, ty = (gcy - acy) / ah;
        float twv = logf(gw / aw), thv = logf(gh / ah);
        s_reg += sl1(tx - p0) + sl1(ty - p1) + sl1(twv - p2) + sl1(thv - p3);
      }
    }
    s_np = (float)npos;
    s_pos = (float)npos * softplus_f(-logit);
    if (allneg) { s_nc = 1.f; s_nl = softplus_f(logit); }
    float pcx = acx + p0 * aw, pcy = acy + p1 * ah;
    float pw = aw * expf(p2), ph = ah * expf(p3);
    float* o = dout + 1 + ((size_t)b * 22500 + n) * 4;
    o[0] = pcx - pw * 0.5f;
    o[1] = pcy - ph * 0.5f;
    o[2] = pcx + pw * 0.5f;
    o[3] = pcy + ph * 0.5f;
  }
  float vals[5] = {s_np, s_reg, s_pos, s_nc, s_nl};
  __shared__ float red[4][5];
#pragma unroll
  for (int q = 0; q < 5; ++q) {
    float v = vals[q];
    for (int o = 32; o; o >>= 1) v += __shfl_down(v, o, 64);
    if ((threadIdx.x & 63) == 0) red[threadIdx.x >> 6][q] = v;
  }
  __syncthreads();
  if (threadIdx.x < 5) {
    float v = red[0][threadIdx.x] + red[1][threadIdx.x] +
              red[2][threadIdx.x] + red[3][threadIdx.x];
    atomicAdd(accum + threadIdx.x, v);
  }
}

// ---------- 5. finalize ----------
__global__ void k_fin(const float* __restrict__ accum, float* __restrict__ dout) {
  if (threadIdx.x == 0 && blockIdx.x == 0) {
    float np = fmaxf(accum[0], 1.f);
    float nn = fmaxf(accum[3], 1.f);
    float loss = 0.5f * (accum[2] / np + accum[4] / nn) + 5.f * (accum[1] / (4.f * np));
    dout[0] = loss;
  }
}

// ---------- launch ----------
extern "C" void kernel_launch(void* const* d_in, const int* in_sizes, int n_in,
                              void* d_out, int out_size, void* d_ws, size_t ws_size,
                              hipStream_t stream) {
  const float* features = (const float*)d_in[0];
  const float* gt_boxes = (const float*)d_in[1];
  const float* w1    = (const float*)d_in[2];
  const float* b1    = (const float*)d_in[3];
  const float* w_cls = (const float*)d_in[4];
  const float* b_cls = (const float*)d_in[5];
  const float* w_box = (const float*)d_in[6];
  const float* b_box = (const float*)d_in[7];
  float* out = (float*)d_out;
  char* ws = (char*)d_ws;

  // ws layout (featT2 chunk-major: 16*16*2704*64 = 44,302,336 B)
  char*           featT2 = ws;                                  // 44,302,336 B
  unsigned short* w2     = (unsigned short*)(ws + 44302336);    //    552,960 B
  float*          wpart  = (float*)(ws + 44855296);             //  7,077,888 B
  float*          oh     = (float*)(ws + 51933184);             //  7,680,000 B
  float*          beff   = (float*)(ws + 59613184);             //        192 B
  unsigned*       mx     = (unsigned*)(ws + 59613376);          //      1,024 B
  float*          accum  = (float*)(ws + 59614400);             //         32 B

  k_featT<<<dim3(21, 4, 16), 256, 0, stream>>>(features, featT2);
  k_weff1<<<dim3(36, 8), 128, 0, stream>>>(w1, w_cls, w_box, wpart, mx);
  k_weff2<<<2536, 256, 0, stream>>>(wpart, w2, w_cls, w_box, b1, b_cls, b_box,
                                    beff, gt_boxes, mx);
  k_conv<<<256, 256, 0, stream>>>(featT2, (const char*)w2, beff, oh);
  k_loss<<<dim3(88, 16), 256, 0, stream>>>(gt_boxes, mx, oh, accum, out);
  k_fin<<<1, 64, 0, stream>>>(accum, out);
}